// Round 1
// baseline (46854.440 us; speedup 1.0000x reference)
//
#include <hip/hip_runtime.h>
#include <math.h>

// Problem constants (match reference)
#define BB   256   // batch
#define TT   64    // timesteps
#define SS   256   // encoder seq len
#define VV   512   // vocab
#define EE   512   // embed dim
#define HH   1024  // hidden
#define ENCE 1024  // encoder dim
#define SUME 2048  // summary dim

// ---------------------------------------------------------------------------
// Tiled fp32 GEMM with dual "concat" inputs:
//   C[M,N] = act( A0[M,K0] @ W0^T + A1[M,Ktot-K0] @ W1^T + b0 (+ b1) )
// W row-major (N, ldw). Requires: K0, Ktot multiples of 16; M, N multiples
// of 64; all pointers 16B aligned; strides multiples of 4 floats.
// Grid: (N/64, M/64), 256 threads. Each thread computes a 4x4 tile.
// ---------------------------------------------------------------------------
__global__ __launch_bounds__(256) void gemm2(
    const float* __restrict__ A0, const float* __restrict__ W0, const int K0,
    const int lda0, const int ldw0,
    const float* __restrict__ A1, const float* __restrict__ W1, const int Ktot,
    const int lda1, const int ldw1,
    const float* __restrict__ b0, const float* __restrict__ b1,
    float* __restrict__ C, const int ldc, const int act)
{
    // Transposed LDS tiles: [k][m] / [k][n] so the inner loop does float4
    // reads that are contiguous across m/n (conflict-light ds_read_b128).
    __shared__ float As[16][68];
    __shared__ float Ws[16][68];

    const int tid = threadIdx.x;
    const int n0  = blockIdx.x * 64;
    const int m0  = blockIdx.y * 64;
    const int lr  = tid >> 2;         // 0..63 : row within tile for loading
    const int lc  = (tid & 3) << 2;   // 0,4,8,12 : k-offset for loading
    const int tx  = tid & 15;         // output col group (n)
    const int ty  = tid >> 4;         // output row group (m)

    float acc[4][4] = {{0.f}};

    for (int k0 = 0; k0 < Ktot; k0 += 16) {
        const float* A; const float* W; int lda, ldw, kk;
        if (k0 < K0) { A = A0; W = W0; lda = lda0; ldw = ldw0; kk = k0; }
        else         { A = A1; W = W1; lda = lda1; ldw = ldw1; kk = k0 - K0; }

        const float4 av = *(const float4*)(A + (size_t)(m0 + lr) * lda + kk + lc);
        const float4 wv = *(const float4*)(W + (size_t)(n0 + lr) * ldw + kk + lc);

        __syncthreads();  // previous iteration's compute done before overwrite
        As[lc + 0][lr] = av.x; As[lc + 1][lr] = av.y;
        As[lc + 2][lr] = av.z; As[lc + 3][lr] = av.w;
        Ws[lc + 0][lr] = wv.x; Ws[lc + 1][lr] = wv.y;
        Ws[lc + 2][lr] = wv.z; Ws[lc + 3][lr] = wv.w;
        __syncthreads();

        #pragma unroll
        for (int p = 0; p < 16; ++p) {
            const float4 a4 = *(const float4*)&As[p][ty * 4];
            const float4 w4 = *(const float4*)&Ws[p][tx * 4];
            acc[0][0] += a4.x * w4.x; acc[0][1] += a4.x * w4.y;
            acc[0][2] += a4.x * w4.z; acc[0][3] += a4.x * w4.w;
            acc[1][0] += a4.y * w4.x; acc[1][1] += a4.y * w4.y;
            acc[1][2] += a4.y * w4.z; acc[1][3] += a4.y * w4.w;
            acc[2][0] += a4.z * w4.x; acc[2][1] += a4.z * w4.y;
            acc[2][2] += a4.z * w4.z; acc[2][3] += a4.z * w4.w;
            acc[3][0] += a4.w * w4.x; acc[3][1] += a4.w * w4.y;
            acc[3][2] += a4.w * w4.z; acc[3][3] += a4.w * w4.w;
        }
    }

    float bias[4];
    #pragma unroll
    for (int j = 0; j < 4; ++j) {
        const int n = n0 + tx * 4 + j;
        bias[j] = b0[n] + (b1 ? b1[n] : 0.f);
    }
    #pragma unroll
    for (int i = 0; i < 4; ++i) {
        const int m = m0 + ty * 4 + i;
        #pragma unroll
        for (int j = 0; j < 4; ++j) {
            float v = acc[i][j] + bias[j];
            if (act) v = tanhf(v);
            C[(size_t)m * ldc + n0 + tx * 4 + j] = v;
        }
    }
}

// ---------------------------------------------------------------------------
// LSTM gate pointwise: g (B,4H) in [i|f|g|o] order; updates h,c in place.
// ---------------------------------------------------------------------------
__global__ void lstm_gate(const float* __restrict__ g,
                          float* __restrict__ h, float* __restrict__ c)
{
    const int i = blockIdx.x * blockDim.x + threadIdx.x;  // over B*H
    if (i >= BB * HH) return;
    const int b = i / HH, k = i % HH;
    const float* gb = g + (size_t)b * 4 * HH;
    const float gi = gb[k];
    const float gf = gb[HH + k];
    const float gg = gb[2 * HH + k];
    const float go = gb[3 * HH + k];
    const float si = 1.f / (1.f + expf(-gi));
    const float sf = 1.f / (1.f + expf(-gf));
    const float so = 1.f / (1.f + expf(-go));
    const float cn = sf * c[i] + si * tanhf(gg);
    c[i] = cn;
    h[i] = so * tanhf(cn);
}

// ---------------------------------------------------------------------------
// Attention, one block per batch row b (256 threads):
//   scores[s] = q[b]·enc[b,s,:]  -> softmax over s -> cross[b,:] = sum attn*enc
// ---------------------------------------------------------------------------
__global__ __launch_bounds__(256) void attn_kernel(
    const float* __restrict__ q, const float* __restrict__ enc,
    float* __restrict__ cross)
{
    const int b = blockIdx.x, tid = threadIdx.x;
    __shared__ float qs[ENCE];
    __shared__ float sc[SS];
    __shared__ float red[256];

    const float* qb = q + (size_t)b * ENCE;
    const float* eb = enc + (size_t)b * SS * ENCE;

    for (int e = tid; e < ENCE; e += 256) qs[e] = qb[e];
    __syncthreads();

    // one score per thread (S == 256 == blockDim)
    {
        const float* row = eb + (size_t)tid * ENCE;
        float a = 0.f;
        for (int e = 0; e < ENCE; e += 4) {
            const float4 ev = *(const float4*)&row[e];
            a += ev.x * qs[e] + ev.y * qs[e + 1] + ev.z * qs[e + 2] + ev.w * qs[e + 3];
        }
        sc[tid] = a;
    }
    __syncthreads();

    // softmax over sc[0..255]
    red[tid] = sc[tid];
    __syncthreads();
    for (int off = 128; off > 0; off >>= 1) {
        if (tid < off) red[tid] = fmaxf(red[tid], red[tid + off]);
        __syncthreads();
    }
    const float mx = red[0];
    __syncthreads();
    const float ex = expf(sc[tid] - mx);
    red[tid] = ex;
    __syncthreads();
    for (int off = 128; off > 0; off >>= 1) {
        if (tid < off) red[tid] += red[tid + off];
        __syncthreads();
    }
    const float inv = 1.f / red[0];
    __syncthreads();
    sc[tid] = ex * inv;
    __syncthreads();

    // weighted sum: thread owns 4 consecutive e's (coalesced float4)
    float4 acc = {0.f, 0.f, 0.f, 0.f};
    const int e0 = tid * 4;
    for (int s = 0; s < SS; ++s) {
        const float w = sc[s];
        const float4 ev = *(const float4*)&eb[(size_t)s * ENCE + e0];
        acc.x += w * ev.x; acc.y += w * ev.y; acc.z += w * ev.z; acc.w += w * ev.w;
    }
    *(float4*)&cross[(size_t)b * ENCE + e0] = acc;
}

// ---------------------------------------------------------------------------
// Output projection + argmax, one block per batch row.
// logits[b,t,:] = lin[b]@Wout^T + bout ; tokens[b,t] = argmax (first max).
// ---------------------------------------------------------------------------
__global__ __launch_bounds__(256) void out_kernel(
    const float* __restrict__ lin, const float* __restrict__ Wout,
    const float* __restrict__ bout, float* __restrict__ tokens,
    float* __restrict__ logits, const int t)
{
    const int b = blockIdx.x, tid = threadIdx.x;
    __shared__ float ls[HH];
    __shared__ float vmax[256];
    __shared__ int   vidx[256];

    const float* lb = lin + (size_t)b * HH;
    for (int e = tid; e < HH; e += 256) ls[e] = lb[e];
    __syncthreads();

    float best = -INFINITY; int bi = 0;
    for (int n = tid; n < VV; n += 256) {
        const float* wr = Wout + (size_t)n * HH;
        float a = bout[n];
        for (int e = 0; e < HH; e += 4) {
            const float4 wv = *(const float4*)&wr[e];
            a += wv.x * ls[e] + wv.y * ls[e + 1] + wv.z * ls[e + 2] + wv.w * ls[e + 3];
        }
        logits[((size_t)b * TT + t) * VV + n] = a;
        if (a > best) { best = a; bi = n; }  // n increasing: keeps first max
    }
    vmax[tid] = best; vidx[tid] = bi;
    __syncthreads();
    for (int off = 128; off > 0; off >>= 1) {
        if (tid < off) {
            const float vo = vmax[tid + off]; const int io = vidx[tid + off];
            if (vo > vmax[tid] || (vo == vmax[tid] && io < vidx[tid])) {
                vmax[tid] = vo; vidx[tid] = io;
            }
        }
        __syncthreads();
    }
    if (tid == 0) tokens[(size_t)b * TT + t] = (float)vidx[0];
}

// ---------------------------------------------------------------------------
// Small helpers
// ---------------------------------------------------------------------------
__global__ void gather_emb(const int* __restrict__ y,
                           const float* __restrict__ table,
                           float* __restrict__ emb, const int t)
{
    const int i = blockIdx.x * blockDim.x + threadIdx.x;  // over B*E
    if (i >= BB * EE) return;
    const int b = i / EE, e = i % EE;
    emb[i] = table[(size_t)y[(size_t)b * TT + t] * EE + e];
}

// init (B,4H) -> h0,h1,c0,c1 per reference reshape(B,2,2,H).permute(1,2,0,3)
__global__ void scatter_init(const float* __restrict__ ini,
                             float* __restrict__ h0, float* __restrict__ h1,
                             float* __restrict__ c0, float* __restrict__ c1)
{
    const int i = blockIdx.x * blockDim.x + threadIdx.x;  // over B*4H
    if (i >= BB * 4 * HH) return;
    const int b = i / (4 * HH), j = i % (4 * HH);
    const int i1 = j / (2 * HH);          // 0: h, 1: c
    const int rem = j % (2 * HH);
    const int i2 = rem / HH;              // layer
    const int k = rem % HH;
    float* dst = (i1 == 0) ? (i2 == 0 ? h0 : h1) : (i2 == 0 ? c0 : c1);
    dst[(size_t)b * HH + k] = ini[i];
}

__global__ void zero_kernel(float* __restrict__ p, const int n)
{
    const int i = blockIdx.x * blockDim.x + threadIdx.x;
    if (i < n) p[i] = 0.f;
}

// ---------------------------------------------------------------------------
extern "C" void kernel_launch(void* const* d_in, const int* in_sizes, int n_in,
                              void* d_out, int out_size, void* d_ws, size_t ws_size,
                              hipStream_t stream)
{
    const int*   y         = (const int*)  d_in[0];
    const float* enc       = (const float*)d_in[1];
    const float* esum      = (const float*)d_in[2];
    const float* emb_table = (const float*)d_in[3];
    const float* W_init    = (const float*)d_in[4];
    const float* b_init    = (const float*)d_in[5];
    const float* W_ci      = (const float*)d_in[6];
    const float* b_ci      = (const float*)d_in[7];
    const float* Wih0      = (const float*)d_in[8];
    const float* Whh0      = (const float*)d_in[9];
    const float* bih0      = (const float*)d_in[10];
    const float* bhh0      = (const float*)d_in[11];
    const float* Wih1      = (const float*)d_in[12];
    const float* Whh1      = (const float*)d_in[13];
    const float* bih1      = (const float*)d_in[14];
    const float* bhh1      = (const float*)d_in[15];
    const float* Wq        = (const float*)d_in[16];
    const float* bq        = (const float*)d_in[17];
    const float* Wco       = (const float*)d_in[18];
    const float* bco       = (const float*)d_in[19];
    const float* Wout      = (const float*)d_in[20];
    const float* bout      = (const float*)d_in[21];

    float* out    = (float*)d_out;
    float* tokens = out;                       // B*T floats (integer-valued)
    float* logits = out + (size_t)BB * TT;     // B*T*V floats

    // workspace carve (floats)
    float* ws    = (float*)d_ws;
    float* h0    = ws;                   // B*H
    float* h1    = h0 + (size_t)BB * HH; // B*H
    float* c0    = h1 + (size_t)BB * HH;
    float* c1    = c0 + (size_t)BB * HH;
    float* cross = c1 + (size_t)BB * HH;    // B*ENC
    float* xbuf  = cross + (size_t)BB * ENCE; // B*E
    float* embb  = xbuf + (size_t)BB * EE;    // B*E
    float* gbuf  = embb + (size_t)BB * EE;    // B*4H (shared by init & gates)
    float* qbuf  = gbuf + (size_t)BB * 4 * HH; // B*ENC (also reused for `lin`)

    const dim3 thr(256);

    // --- decoder_init: tanh(esum @ W_init^T + b_init) -> scatter to h/c ---
    gemm2<<<dim3(4 * HH / 64, BB / 64), thr, 0, stream>>>(
        esum, W_init, SUME, SUME, SUME,
        nullptr, nullptr, SUME, 0, 0,
        b_init, nullptr, gbuf, 4 * HH, 1);
    scatter_init<<<dim3(BB * 4 * HH / 256), thr, 0, stream>>>(gbuf, h0, h1, c0, c1);
    zero_kernel<<<dim3(BB * ENCE / 256), thr, 0, stream>>>(cross, BB * ENCE);

    for (int t = 0; t < TT; ++t) {
        // emb = emb_table[y[:,t]]
        gather_emb<<<dim3(BB * EE / 256), thr, 0, stream>>>(y, emb_table, embb, t);

        // x = tanh([emb, cross] @ W_ci^T + b_ci)   (W_ci is (E, E+ENC))
        gemm2<<<dim3(EE / 64, BB / 64), thr, 0, stream>>>(
            embb, W_ci, EE, EE, EE + ENCE,
            cross, W_ci + EE, EE + ENCE, ENCE, EE + ENCE,
            b_ci, nullptr, xbuf, EE, 1);

        // layer0 gates: g = x@Wih0^T + h0@Whh0^T + bih0 + bhh0
        gemm2<<<dim3(4 * HH / 64, BB / 64), thr, 0, stream>>>(
            xbuf, Wih0, EE, EE, EE,
            h0, Whh0, EE + HH, HH, HH,
            bih0, bhh0, gbuf, 4 * HH, 0);
        lstm_gate<<<dim3(BB * HH / 256), thr, 0, stream>>>(gbuf, h0, c0);

        // layer1 gates: g = h0@Wih1^T + h1@Whh1^T + bih1 + bhh1
        gemm2<<<dim3(4 * HH / 64, BB / 64), thr, 0, stream>>>(
            h0, Wih1, HH, HH, HH,
            h1, Whh1, 2 * HH, HH, HH,
            bih1, bhh1, gbuf, 4 * HH, 0);
        lstm_gate<<<dim3(BB * HH / 256), thr, 0, stream>>>(gbuf, h1, c1);

        // q = tanh([h1, c1] @ Wq^T + bq)   (Wq is (ENC, 2H))
        gemm2<<<dim3(ENCE / 64, BB / 64), thr, 0, stream>>>(
            h1, Wq, HH, HH, 2 * HH,
            c1, Wq + HH, 2 * HH, HH, 2 * HH,
            bq, nullptr, qbuf, ENCE, 1);

        // attention -> cross
        attn_kernel<<<dim3(BB), thr, 0, stream>>>(qbuf, enc, cross);

        // lin = tanh([h1, cross] @ Wco^T + bco)   (Wco is (H, ENC+H)); reuse qbuf
        gemm2<<<dim3(HH / 64, BB / 64), thr, 0, stream>>>(
            h1, Wco, HH, HH, ENCE + HH,
            cross, Wco + HH, ENCE + HH, ENCE, ENCE + HH,
            bco, nullptr, qbuf, HH, 1);

        // logits + argmax
        out_kernel<<<dim3(BB), thr, 0, stream>>>(qbuf, Wout, bout, tokens, logits, t);
    }
}

// Round 3
// 20274.124 us; speedup vs baseline: 2.3110x; 2.3110x over previous
//
#include <hip/hip_runtime.h>
#include <math.h>

// Problem constants (match reference)
#define BB   256   // batch
#define TT   64    // timesteps
#define SS   256   // encoder seq len
#define VV   512   // vocab
#define EE   512   // embed dim
#define HH   1024  // hidden
#define ENCE 1024  // encoder dim
#define SUME 2048  // summary dim

typedef __attribute__((ext_vector_type(8))) short bf8v;    // 8 bf16 (4 VGPR)
typedef __attribute__((ext_vector_type(4))) float f4v;

__device__ __forceinline__ unsigned short f2b_hi(float x) {
    unsigned int u = __float_as_uint(x);
    return (unsigned short)((u + 0x7fffu + ((u >> 16) & 1)) >> 16);
}
__device__ __forceinline__ float b2f(unsigned short h) {
    return __uint_as_float(((unsigned int)h) << 16);
}

// ===========================================================================
// LEGACY fp32 path (round-0/1, known-good). decoder_init always; full
// fallback when ws_size is too small for the MFMA buffers.
// ===========================================================================
__global__ __launch_bounds__(256) void gemm2(
    const float* __restrict__ A0, const float* __restrict__ W0, const int K0,
    const int lda0, const int ldw0,
    const float* __restrict__ A1, const float* __restrict__ W1, const int Ktot,
    const int lda1, const int ldw1,
    const float* __restrict__ b0, const float* __restrict__ b1,
    float* __restrict__ C, const int ldc, const int act)
{
    __shared__ float As[16][68];
    __shared__ float Ws[16][68];

    const int tid = threadIdx.x;
    const int n0  = blockIdx.x * 64;
    const int m0  = blockIdx.y * 64;
    const int lr  = tid >> 2;
    const int lc  = (tid & 3) << 2;
    const int tx  = tid & 15;
    const int ty  = tid >> 4;

    float acc[4][4] = {{0.f}};

    for (int k0 = 0; k0 < Ktot; k0 += 16) {
        const float* A; const float* W; int lda, ldw, kk;
        if (k0 < K0) { A = A0; W = W0; lda = lda0; ldw = ldw0; kk = k0; }
        else         { A = A1; W = W1; lda = lda1; ldw = ldw1; kk = k0 - K0; }

        const float4 av = *(const float4*)(A + (size_t)(m0 + lr) * lda + kk + lc);
        const float4 wv = *(const float4*)(W + (size_t)(n0 + lr) * ldw + kk + lc);

        __syncthreads();
        As[lc + 0][lr] = av.x; As[lc + 1][lr] = av.y;
        As[lc + 2][lr] = av.z; As[lc + 3][lr] = av.w;
        Ws[lc + 0][lr] = wv.x; Ws[lc + 1][lr] = wv.y;
        Ws[lc + 2][lr] = wv.z; Ws[lc + 3][lr] = wv.w;
        __syncthreads();

        #pragma unroll
        for (int p = 0; p < 16; ++p) {
            const float4 a4 = *(const float4*)&As[p][ty * 4];
            const float4 w4 = *(const float4*)&Ws[p][tx * 4];
            acc[0][0] += a4.x * w4.x; acc[0][1] += a4.x * w4.y;
            acc[0][2] += a4.x * w4.z; acc[0][3] += a4.x * w4.w;
            acc[1][0] += a4.y * w4.x; acc[1][1] += a4.y * w4.y;
            acc[1][2] += a4.y * w4.z; acc[1][3] += a4.y * w4.w;
            acc[2][0] += a4.z * w4.x; acc[2][1] += a4.z * w4.y;
            acc[2][2] += a4.z * w4.z; acc[2][3] += a4.z * w4.w;
            acc[3][0] += a4.w * w4.x; acc[3][1] += a4.w * w4.y;
            acc[3][2] += a4.w * w4.z; acc[3][3] += a4.w * w4.w;
        }
    }

    float bias[4];
    #pragma unroll
    for (int j = 0; j < 4; ++j) {
        const int n = n0 + tx * 4 + j;
        bias[j] = b0[n] + (b1 ? b1[n] : 0.f);
    }
    #pragma unroll
    for (int i = 0; i < 4; ++i) {
        const int m = m0 + ty * 4 + i;
        #pragma unroll
        for (int j = 0; j < 4; ++j) {
            float v = acc[i][j] + bias[j];
            if (act) v = tanhf(v);
            C[(size_t)m * ldc + n0 + tx * 4 + j] = v;
        }
    }
}

__global__ void lstm_gate(const float* __restrict__ g,
                          float* __restrict__ h, float* __restrict__ c)
{
    const int i = blockIdx.x * blockDim.x + threadIdx.x;
    if (i >= BB * HH) return;
    const int b = i / HH, k = i % HH;
    const float* gb = g + (size_t)b * 4 * HH;
    const float gi = gb[k];
    const float gf = gb[HH + k];
    const float gg = gb[2 * HH + k];
    const float go = gb[3 * HH + k];
    const float si = 1.f / (1.f + expf(-gi));
    const float sf = 1.f / (1.f + expf(-gf));
    const float so = 1.f / (1.f + expf(-go));
    const float cn = sf * c[i] + si * tanhf(gg);
    c[i] = cn;
    h[i] = so * tanhf(cn);
}

// Known-good fp32 attention (round-1 PASS).
__global__ __launch_bounds__(256) void attn_kernel(
    const float* __restrict__ q, const float* __restrict__ enc,
    float* __restrict__ cross)
{
    const int b = blockIdx.x, tid = threadIdx.x;
    __shared__ float qs[ENCE];
    __shared__ float sc[SS];
    __shared__ float red[256];

    const float* qb = q + (size_t)b * ENCE;
    const float* eb = enc + (size_t)b * SS * ENCE;

    for (int e = tid; e < ENCE; e += 256) qs[e] = qb[e];
    __syncthreads();

    {
        const float* row = eb + (size_t)tid * ENCE;
        float a = 0.f;
        for (int e = 0; e < ENCE; e += 4) {
            const float4 ev = *(const float4*)&row[e];
            a += ev.x * qs[e] + ev.y * qs[e + 1] + ev.z * qs[e + 2] + ev.w * qs[e + 3];
        }
        sc[tid] = a;
    }
    __syncthreads();

    red[tid] = sc[tid];
    __syncthreads();
    for (int off = 128; off > 0; off >>= 1) {
        if (tid < off) red[tid] = fmaxf(red[tid], red[tid + off]);
        __syncthreads();
    }
    const float mx = red[0];
    __syncthreads();
    const float ex = expf(sc[tid] - mx);
    red[tid] = ex;
    __syncthreads();
    for (int off = 128; off > 0; off >>= 1) {
        if (tid < off) red[tid] += red[tid + off];
        __syncthreads();
    }
    const float inv = 1.f / red[0];
    __syncthreads();
    sc[tid] = ex * inv;
    __syncthreads();

    float4 acc = {0.f, 0.f, 0.f, 0.f};
    const int e0 = tid * 4;
    for (int s = 0; s < SS; ++s) {
        const float w = sc[s];
        const float4 ev = *(const float4*)&eb[(size_t)s * ENCE + e0];
        acc.x += w * ev.x; acc.y += w * ev.y; acc.z += w * ev.z; acc.w += w * ev.w;
    }
    *(float4*)&cross[(size_t)b * ENCE + e0] = acc;
}

__global__ __launch_bounds__(256) void out_kernel(
    const float* __restrict__ lin, const float* __restrict__ Wout,
    const float* __restrict__ bout, float* __restrict__ tokens,
    float* __restrict__ logits, const int t)
{
    const int b = blockIdx.x, tid = threadIdx.x;
    __shared__ float ls[HH];
    __shared__ float vmax[256];
    __shared__ int   vidx[256];

    const float* lb = lin + (size_t)b * HH;
    for (int e = tid; e < HH; e += 256) ls[e] = lb[e];
    __syncthreads();

    float best = -INFINITY; int bi = 0;
    for (int n = tid; n < VV; n += 256) {
        const float* wr = Wout + (size_t)n * HH;
        float a = bout[n];
        for (int e = 0; e < HH; e += 4) {
            const float4 wv = *(const float4*)&wr[e];
            a += wv.x * ls[e] + wv.y * ls[e + 1] + wv.z * ls[e + 2] + wv.w * ls[e + 3];
        }
        logits[((size_t)b * TT + t) * VV + n] = a;
        if (a > best) { best = a; bi = n; }
    }
    vmax[tid] = best; vidx[tid] = bi;
    __syncthreads();
    for (int off = 128; off > 0; off >>= 1) {
        if (tid < off) {
            const float vo = vmax[tid + off]; const int io = vidx[tid + off];
            if (vo > vmax[tid] || (vo == vmax[tid] && io < vidx[tid])) {
                vmax[tid] = vo; vidx[tid] = io;
            }
        }
        __syncthreads();
    }
    if (tid == 0) tokens[(size_t)b * TT + t] = (float)vidx[0];
}

__global__ void gather_emb(const int* __restrict__ y,
                           const float* __restrict__ table,
                           float* __restrict__ emb, const int t)
{
    const int i = blockIdx.x * blockDim.x + threadIdx.x;
    if (i >= BB * EE) return;
    const int b = i / EE, e = i % EE;
    emb[i] = table[(size_t)y[(size_t)b * TT + t] * EE + e];
}

__global__ void scatter_init(const float* __restrict__ ini,
                             float* __restrict__ h0, float* __restrict__ h1,
                             float* __restrict__ c0, float* __restrict__ c1)
{
    const int i = blockIdx.x * blockDim.x + threadIdx.x;
    if (i >= BB * 4 * HH) return;
    const int b = i / (4 * HH), j = i % (4 * HH);
    const int i1 = j / (2 * HH);
    const int rem = j % (2 * HH);
    const int i2 = rem / HH;
    const int k = rem % HH;
    float* dst = (i1 == 0) ? (i2 == 0 ? h0 : h1) : (i2 == 0 ? c0 : c1);
    dst[(size_t)b * HH + k] = ini[i];
}

__global__ void zero_kernel(float* __restrict__ p, const int n)
{
    const int i = blockIdx.x * blockDim.x + threadIdx.x;
    if (i < n) p[i] = 0.f;
}

// ===========================================================================
// 3-split bf16 MFMA path (fp32-grade accuracy: missing terms ~2^-27)
// ===========================================================================

// fp32 -> (hi, mid, lo) bf16 triple, packed into a column slice of [N][dld].
__global__ void conv_w3(const float* __restrict__ src, const int N, const int K,
                        unsigned short* __restrict__ dh,
                        unsigned short* __restrict__ dm,
                        unsigned short* __restrict__ dl,
                        const int dld, const int coff)
{
    const int total = N * K;
    for (int i = blockIdx.x * blockDim.x + threadIdx.x; i < total;
         i += gridDim.x * blockDim.x) {
        const int n = i / K, k = i - n * K;
        const float x = src[i];
        const unsigned short hb = f2b_hi(x);
        const float r1 = x - b2f(hb);
        const unsigned short mb = f2b_hi(r1);
        const float r2 = r1 - b2f(mb);
        const unsigned short lb = f2b_hi(r2);
        const size_t o = (size_t)n * dld + coff + k;
        dh[o] = hb; dm[o] = mb; dl[o] = lb;
    }
}

// 3-split MFMA GEMM, split-K partials:
//   Cpart[p][M=256][N] = A[M, kbeg:kend] @ W[N, kbeg:kend]^T
// A fp32 dual-source concat (col < K0 -> A0 else A1), split hi/mid/lo on the
// fly. W pre-split. 6 passes: hh + hm + mh + mm + hl + lh  (error ~2^-27).
// Block: 256 thr = 4 waves (2m x 2n), tile 64x128, BK=32.
// Grid: (N/128, 256/64, P), chunk = Kt/P (multiple of 32).
__global__ __launch_bounds__(256) void gemm_mfma6(
    const float* __restrict__ A0, const int lda0,
    const float* __restrict__ A1, const int lda1, const int K0,
    const unsigned short* __restrict__ Wh, const unsigned short* __restrict__ Wm,
    const unsigned short* __restrict__ Wl,
    const int Kt, float* __restrict__ Cpart, const int N, const int chunk)
{
    // rows padded to 40 shorts (80B = 16B-aligned)
    __shared__ short Ah[64][40], Am[64][40], Al[64][40];
    __shared__ short Wsh[128][40], Wsm[128][40], Wsl[128][40];

    const int tid = threadIdx.x;
    const int n0 = blockIdx.x * 128;
    const int m0 = blockIdx.y * 64;
    const int p  = blockIdx.z;
    const int kbeg = p * chunk, kend = kbeg + chunk;

    const int lane = tid & 63, wave = tid >> 6;
    const int wm = wave >> 1, wn = wave & 1;
    const int l15 = lane & 15, lg = lane >> 4;

    const int ar = tid >> 2, ag = tid & 3;     // staging: row 0..63, k-grp 0..3

    f4v acc[2][4];
    #pragma unroll
    for (int i = 0; i < 2; ++i)
        #pragma unroll
        for (int j = 0; j < 4; ++j) acc[i][j] = (f4v){0.f, 0.f, 0.f, 0.f};

    for (int kk = kbeg; kk < kend; kk += 32) {
        // ---- issue global loads ----
        const int acol = kk + ag * 8;
        const float* Arow; int ac;
        if (acol < K0) { Arow = A0 + (size_t)(m0 + ar) * lda0; ac = acol; }
        else           { Arow = A1 + (size_t)(m0 + ar) * lda1; ac = acol - K0; }
        const float4 av0 = *(const float4*)(Arow + ac);
        const float4 av1 = *(const float4*)(Arow + ac + 4);

        const size_t o0 = (size_t)(n0 + ar) * Kt + kk + ag * 8;
        const size_t o1 = (size_t)(n0 + 64 + ar) * Kt + kk + ag * 8;
        const uint4 wh0 = *(const uint4*)(Wh + o0);
        const uint4 wm0 = *(const uint4*)(Wm + o0);
        const uint4 wl0 = *(const uint4*)(Wl + o0);
        const uint4 wh1 = *(const uint4*)(Wh + o1);
        const uint4 wm1 = *(const uint4*)(Wm + o1);
        const uint4 wl1 = *(const uint4*)(Wl + o1);

        __syncthreads();  // prior iteration's frag reads done

        {   // A: split 8 floats -> hi/mid/lo bf16x8
            bf8v vh, vm, vl;
            const float xs[8] = {av0.x, av0.y, av0.z, av0.w,
                                 av1.x, av1.y, av1.z, av1.w};
            #pragma unroll
            for (int j = 0; j < 8; ++j) {
                const unsigned short hb = f2b_hi(xs[j]);
                const float r1 = xs[j] - b2f(hb);
                const unsigned short mb = f2b_hi(r1);
                const float r2 = r1 - b2f(mb);
                vh[j] = (short)hb;
                vm[j] = (short)mb;
                vl[j] = (short)f2b_hi(r2);
            }
            *(bf8v*)&Ah[ar][ag * 8] = vh;
            *(bf8v*)&Am[ar][ag * 8] = vm;
            *(bf8v*)&Al[ar][ag * 8] = vl;
        }
        *(uint4*)&Wsh[ar][ag * 8] = wh0;
        *(uint4*)&Wsm[ar][ag * 8] = wm0;
        *(uint4*)&Wsl[ar][ag * 8] = wl0;
        *(uint4*)&Wsh[64 + ar][ag * 8] = wh1;
        *(uint4*)&Wsm[64 + ar][ag * 8] = wm1;
        *(uint4*)&Wsl[64 + ar][ag * 8] = wl1;

        __syncthreads();

        bf8v afh[2], afm[2], afl[2];
        #pragma unroll
        for (int fr = 0; fr < 2; ++fr) {
            const int r = wm * 32 + fr * 16 + l15;
            afh[fr] = *(const bf8v*)&Ah[r][lg * 8];
            afm[fr] = *(const bf8v*)&Am[r][lg * 8];
            afl[fr] = *(const bf8v*)&Al[r][lg * 8];
        }
        #pragma unroll
        for (int fn = 0; fn < 4; ++fn) {
            const int r = wn * 64 + fn * 16 + l15;
            const bf8v wfh = *(const bf8v*)&Wsh[r][lg * 8];
            const bf8v wfm = *(const bf8v*)&Wsm[r][lg * 8];
            const bf8v wfl = *(const bf8v*)&Wsl[r][lg * 8];
            #pragma unroll
            for (int fr = 0; fr < 2; ++fr) {
                acc[fr][fn] = __builtin_amdgcn_mfma_f32_16x16x32_bf16(
                    afl[fr], wfh, acc[fr][fn], 0, 0, 0);
                acc[fr][fn] = __builtin_amdgcn_mfma_f32_16x16x32_bf16(
                    afh[fr], wfl, acc[fr][fn], 0, 0, 0);
                acc[fr][fn] = __builtin_amdgcn_mfma_f32_16x16x32_bf16(
                    afm[fr], wfm, acc[fr][fn], 0, 0, 0);
                acc[fr][fn] = __builtin_amdgcn_mfma_f32_16x16x32_bf16(
                    afm[fr], wfh, acc[fr][fn], 0, 0, 0);
                acc[fr][fn] = __builtin_amdgcn_mfma_f32_16x16x32_bf16(
                    afh[fr], wfm, acc[fr][fn], 0, 0, 0);
                acc[fr][fn] = __builtin_amdgcn_mfma_f32_16x16x32_bf16(
                    afh[fr], wfh, acc[fr][fn], 0, 0, 0);
            }
        }
    }

    // epilogue: C/D layout col=lane&15, row=(lane>>4)*4+reg
    float* slab = Cpart + (size_t)p * BB * N;
    #pragma unroll
    for (int fr = 0; fr < 2; ++fr) {
        const int row0 = m0 + wm * 32 + fr * 16 + lg * 4;
        #pragma unroll
        for (int fn = 0; fn < 4; ++fn) {
            const int col = n0 + wn * 64 + fn * 16 + l15;
            #pragma unroll
            for (int j = 0; j < 4; ++j)
                slab[(size_t)(row0 + j) * N + col] = acc[fr][fn][j];
        }
    }
}

// split-K reduce + bias + tanh
__global__ void ep_tanh(const float* __restrict__ part, const int P,
                        const float* __restrict__ bias, float* __restrict__ dst,
                        const int total, const int N)
{
    for (int i = blockIdx.x * blockDim.x + threadIdx.x; i < total;
         i += gridDim.x * blockDim.x) {
        const int n = i % N;
        float s = bias[n];
        for (int p = 0; p < P; ++p) s += part[(size_t)p * total + i];
        dst[i] = tanhf(s);
    }
}

// split-K reduce + biases + LSTM gate pointwise (updates h, c in place)
__global__ void ep_gate(const float* __restrict__ part, const int P,
                        const float* __restrict__ bih, const float* __restrict__ bhh,
                        float* __restrict__ h, float* __restrict__ c)
{
    const int i = blockIdx.x * blockDim.x + threadIdx.x;
    if (i >= BB * HH) return;
    const int b = i >> 10, k = i & (HH - 1);
    const size_t base = (size_t)b * 4 * HH;
    float gi = bih[k] + bhh[k];
    float gf = bih[HH + k] + bhh[HH + k];
    float gg = bih[2 * HH + k] + bhh[2 * HH + k];
    float go = bih[3 * HH + k] + bhh[3 * HH + k];
    for (int p = 0; p < P; ++p) {
        const float* gp = part + (size_t)p * BB * 4 * HH + base;
        gi += gp[k]; gf += gp[HH + k]; gg += gp[2 * HH + k]; go += gp[3 * HH + k];
    }
    const float si = 1.f / (1.f + expf(-gi));
    const float sf = 1.f / (1.f + expf(-gf));
    const float so = 1.f / (1.f + expf(-go));
    const float cn = sf * c[i] + si * tanhf(gg);
    c[i] = cn;
    h[i] = so * tanhf(cn);
}

// ===========================================================================
extern "C" void kernel_launch(void* const* d_in, const int* in_sizes, int n_in,
                              void* d_out, int out_size, void* d_ws, size_t ws_size,
                              hipStream_t stream)
{
    const int*   y         = (const int*)  d_in[0];
    const float* enc       = (const float*)d_in[1];
    const float* esum      = (const float*)d_in[2];
    const float* emb_table = (const float*)d_in[3];
    const float* W_init    = (const float*)d_in[4];
    const float* b_init    = (const float*)d_in[5];
    const float* W_ci      = (const float*)d_in[6];
    const float* b_ci      = (const float*)d_in[7];
    const float* Wih0      = (const float*)d_in[8];
    const float* Whh0      = (const float*)d_in[9];
    const float* bih0      = (const float*)d_in[10];
    const float* bhh0      = (const float*)d_in[11];
    const float* Wih1      = (const float*)d_in[12];
    const float* Whh1      = (const float*)d_in[13];
    const float* bih1      = (const float*)d_in[14];
    const float* bhh1      = (const float*)d_in[15];
    const float* Wq        = (const float*)d_in[16];
    const float* bq        = (const float*)d_in[17];
    const float* Wco       = (const float*)d_in[18];
    const float* bco       = (const float*)d_in[19];
    const float* Wout      = (const float*)d_in[20];
    const float* bout      = (const float*)d_in[21];

    float* out    = (float*)d_out;
    float* tokens = out;
    float* logits = out + (size_t)BB * TT;

    // ---- workspace carve ----
    char* wsb = (char*)d_ws;
    size_t off = 0;
    auto alloc = [&](size_t bytes) -> char* {
        char* p = wsb + off;
        off = (off + bytes + 255) & ~(size_t)255;
        return p;
    };
    float* h0    = (float*)alloc((size_t)BB * HH * 4);
    float* h1    = (float*)alloc((size_t)BB * HH * 4);
    float* c0    = (float*)alloc((size_t)BB * HH * 4);
    float* c1    = (float*)alloc((size_t)BB * HH * 4);
    float* cross = (float*)alloc((size_t)BB * ENCE * 4);
    float* xbuf  = (float*)alloc((size_t)BB * EE * 4);
    float* embb  = (float*)alloc((size_t)BB * EE * 4);
    float* gbuf  = (float*)alloc((size_t)BB * 4 * HH * 4);
    float* qbuf  = (float*)alloc((size_t)BB * ENCE * 4);

    float* part = (float*)alloc((size_t)4 * BB * 4 * HH * 4);   // 16 MiB

    // 3-split weight buffers (hi/mid/lo), row-major [N][ld]
    unsigned short *ci_s[3], *g0_s[3], *g1_s[3], *wq_s[3], *wc_s[3];
    for (int s = 0; s < 3; ++s) ci_s[s] = (unsigned short*)alloc((size_t)EE * 1536 * 2);
    for (int s = 0; s < 3; ++s) g0_s[s] = (unsigned short*)alloc((size_t)4 * HH * 1536 * 2);
    for (int s = 0; s < 3; ++s) g1_s[s] = (unsigned short*)alloc((size_t)4 * HH * 2048 * 2);
    for (int s = 0; s < 3; ++s) wq_s[s] = (unsigned short*)alloc((size_t)ENCE * 2048 * 2);
    for (int s = 0; s < 3; ++s) wc_s[s] = (unsigned short*)alloc((size_t)HH * 2048 * 2);
    const size_t need_mfma = off;

    const int mfma_ok = (ws_size >= need_mfma);

    const dim3 thr(256);

    // ---- decoder_init (fp32, once) ----
    gemm2<<<dim3(4 * HH / 64, BB / 64), thr, 0, stream>>>(
        esum, W_init, SUME, SUME, SUME,
        nullptr, nullptr, SUME, 0, 0,
        b_init, nullptr, gbuf, 4 * HH, 1);
    scatter_init<<<dim3(BB * 4 * HH / 256), thr, 0, stream>>>(gbuf, h0, h1, c0, c1);
    zero_kernel<<<dim3(BB * ENCE / 256), thr, 0, stream>>>(cross, BB * ENCE);

    if (!mfma_ok) {
        // -------- legacy full-fp32 path (round-1 PASS) --------
        for (int t = 0; t < TT; ++t) {
            gather_emb<<<dim3(BB * EE / 256), thr, 0, stream>>>(y, emb_table, embb, t);
            gemm2<<<dim3(EE / 64, BB / 64), thr, 0, stream>>>(
                embb, W_ci, EE, EE, EE + ENCE,
                cross, W_ci + EE, EE + ENCE, ENCE, EE + ENCE,
                b_ci, nullptr, xbuf, EE, 1);
            gemm2<<<dim3(4 * HH / 64, BB / 64), thr, 0, stream>>>(
                xbuf, Wih0, EE, EE, EE,
                h0, Whh0, EE + HH, HH, HH,
                bih0, bhh0, gbuf, 4 * HH, 0);
            lstm_gate<<<dim3(BB * HH / 256), thr, 0, stream>>>(gbuf, h0, c0);
            gemm2<<<dim3(4 * HH / 64, BB / 64), thr, 0, stream>>>(
                h0, Wih1, HH, HH, HH,
                h1, Whh1, 2 * HH, HH, HH,
                bih1, bhh1, gbuf, 4 * HH, 0);
            lstm_gate<<<dim3(BB * HH / 256), thr, 0, stream>>>(gbuf, h1, c1);
            gemm2<<<dim3(ENCE / 64, BB / 64), thr, 0, stream>>>(
                h1, Wq, HH, HH, 2 * HH,
                c1, Wq + HH, 2 * HH, HH, 2 * HH,
                bq, nullptr, qbuf, ENCE, 1);
            attn_kernel<<<dim3(BB), thr, 0, stream>>>(qbuf, enc, cross);
            gemm2<<<dim3(HH / 64, BB / 64), thr, 0, stream>>>(
                h1, Wco, HH, HH, ENCE + HH,
                cross, Wco + HH, ENCE + HH, ENCE, ENCE + HH,
                bco, nullptr, qbuf, HH, 1);
            out_kernel<<<dim3(BB), thr, 0, stream>>>(qbuf, Wout, bout, tokens, logits, t);
        }
        return;
    }

    // ---- one-time weight 3-splits (every call; deterministic) ----
    const dim3 cg(4096);
    conv_w3<<<cg, thr, 0, stream>>>(W_ci, EE, EE + ENCE, ci_s[0], ci_s[1], ci_s[2], 1536, 0);
    conv_w3<<<cg, thr, 0, stream>>>(Wih0, 4 * HH, EE, g0_s[0], g0_s[1], g0_s[2], 1536, 0);
    conv_w3<<<cg, thr, 0, stream>>>(Whh0, 4 * HH, HH, g0_s[0], g0_s[1], g0_s[2], 1536, EE);
    conv_w3<<<cg, thr, 0, stream>>>(Wih1, 4 * HH, HH, g1_s[0], g1_s[1], g1_s[2], 2048, 0);
    conv_w3<<<cg, thr, 0, stream>>>(Whh1, 4 * HH, HH, g1_s[0], g1_s[1], g1_s[2], 2048, HH);
    conv_w3<<<cg, thr, 0, stream>>>(Wq, ENCE, 2 * HH, wq_s[0], wq_s[1], wq_s[2], 2048, 0);
    conv_w3<<<cg, thr, 0, stream>>>(Wco, HH, ENCE + HH, wc_s[0], wc_s[1], wc_s[2], 2048, 0);

    auto gemmS = [&](const float* A0, int lda0, const float* A1, int lda1, int K0,
                     unsigned short* const* Ws, int Kt, int N, int P) {
        gemm_mfma6<<<dim3(N / 128, BB / 64, P), thr, 0, stream>>>(
            A0, lda0, A1, lda1, K0, Ws[0], Ws[1], Ws[2], Kt, part, N, Kt / P);
    };

    for (int t = 0; t < TT; ++t) {
        gather_emb<<<dim3(BB * EE / 256), thr, 0, stream>>>(y, emb_table, embb, t);

        // x = tanh([emb | cross] @ Wci^T + b_ci)
        gemmS(embb, EE, cross, ENCE, EE, ci_s, 1536, EE, 16);
        ep_tanh<<<dim3(512), thr, 0, stream>>>(part, 16, b_ci, xbuf, BB * EE, EE);

        // layer0 gates
        gemmS(xbuf, EE, h0, HH, EE, g0_s, 1536, 4 * HH, 4);
        ep_gate<<<dim3(BB * HH / 256), thr, 0, stream>>>(part, 4, bih0, bhh0, h0, c0);

        // layer1 gates
        gemmS(h0, HH, h1, HH, HH, g1_s, 2048, 4 * HH, 4);
        ep_gate<<<dim3(BB * HH / 256), thr, 0, stream>>>(part, 4, bih1, bhh1, h1, c1);

        // q = tanh([h1 | c1] @ Wq^T + bq)
        gemmS(h1, HH, c1, HH, HH, wq_s, 2048, ENCE, 8);
        ep_tanh<<<dim3(1024), thr, 0, stream>>>(part, 8, bq, qbuf, BB * ENCE, ENCE);

        // attention -> cross (fp32, known-good)
        attn_kernel<<<dim3(BB), thr, 0, stream>>>(qbuf, enc, cross);

        // lin = tanh([h1 | cross] @ Wco^T + bco)
        gemmS(h1, HH, cross, ENCE, HH, wc_s, 2048, HH, 8);
        ep_tanh<<<dim3(1024), thr, 0, stream>>>(part, 8, bco, qbuf, BB * HH, HH);

        // logits + argmax
        out_kernel<<<dim3(BB), thr, 0, stream>>>(qbuf, Wout, bout, tokens, logits, t);
    }
}

// Round 4
// 17893.491 us; speedup vs baseline: 2.6185x; 1.1330x over previous
//
#include <hip/hip_runtime.h>
#include <math.h>

// Problem constants (match reference)
#define BB   256   // batch
#define TT   64    // timesteps
#define SS   256   // encoder seq len
#define VV   512   // vocab
#define EE   512   // embed dim
#define HH   1024  // hidden
#define ENCE 1024  // encoder dim
#define SUME 2048  // summary dim

typedef __attribute__((ext_vector_type(8))) short bf8v;    // 8 bf16 (4 VGPR)
typedef __attribute__((ext_vector_type(4))) float f4v;

__device__ __forceinline__ unsigned short f2b_hi(float x) {
    unsigned int u = __float_as_uint(x);
    return (unsigned short)((u + 0x7fffu + ((u >> 16) & 1)) >> 16);
}
__device__ __forceinline__ float b2f(unsigned short h) {
    return __uint_as_float(((unsigned int)h) << 16);
}

// ===========================================================================
// LEGACY fp32 path (known-good): decoder_init always; full fallback if ws
// too small.
// ===========================================================================
__global__ __launch_bounds__(256) void gemm2(
    const float* __restrict__ A0, const float* __restrict__ W0, const int K0,
    const int lda0, const int ldw0,
    const float* __restrict__ A1, const float* __restrict__ W1, const int Ktot,
    const int lda1, const int ldw1,
    const float* __restrict__ b0, const float* __restrict__ b1,
    float* __restrict__ C, const int ldc, const int act)
{
    __shared__ float As[16][68];
    __shared__ float Ws[16][68];

    const int tid = threadIdx.x;
    const int n0  = blockIdx.x * 64;
    const int m0  = blockIdx.y * 64;
    const int lr  = tid >> 2;
    const int lc  = (tid & 3) << 2;
    const int tx  = tid & 15;
    const int ty  = tid >> 4;

    float acc[4][4] = {{0.f}};

    for (int k0 = 0; k0 < Ktot; k0 += 16) {
        const float* A; const float* W; int lda, ldw, kk;
        if (k0 < K0) { A = A0; W = W0; lda = lda0; ldw = ldw0; kk = k0; }
        else         { A = A1; W = W1; lda = lda1; ldw = ldw1; kk = k0 - K0; }

        const float4 av = *(const float4*)(A + (size_t)(m0 + lr) * lda + kk + lc);
        const float4 wv = *(const float4*)(W + (size_t)(n0 + lr) * ldw + kk + lc);

        __syncthreads();
        As[lc + 0][lr] = av.x; As[lc + 1][lr] = av.y;
        As[lc + 2][lr] = av.z; As[lc + 3][lr] = av.w;
        Ws[lc + 0][lr] = wv.x; Ws[lc + 1][lr] = wv.y;
        Ws[lc + 2][lr] = wv.z; Ws[lc + 3][lr] = wv.w;
        __syncthreads();

        #pragma unroll
        for (int p = 0; p < 16; ++p) {
            const float4 a4 = *(const float4*)&As[p][ty * 4];
            const float4 w4 = *(const float4*)&Ws[p][tx * 4];
            acc[0][0] += a4.x * w4.x; acc[0][1] += a4.x * w4.y;
            acc[0][2] += a4.x * w4.z; acc[0][3] += a4.x * w4.w;
            acc[1][0] += a4.y * w4.x; acc[1][1] += a4.y * w4.y;
            acc[1][2] += a4.y * w4.z; acc[1][3] += a4.y * w4.w;
            acc[2][0] += a4.z * w4.x; acc[2][1] += a4.z * w4.y;
            acc[2][2] += a4.z * w4.z; acc[2][3] += a4.z * w4.w;
            acc[3][0] += a4.w * w4.x; acc[3][1] += a4.w * w4.y;
            acc[3][2] += a4.w * w4.z; acc[3][3] += a4.w * w4.w;
        }
    }

    float bias[4];
    #pragma unroll
    for (int j = 0; j < 4; ++j) {
        const int n = n0 + tx * 4 + j;
        bias[j] = b0[n] + (b1 ? b1[n] : 0.f);
    }
    #pragma unroll
    for (int i = 0; i < 4; ++i) {
        const int m = m0 + ty * 4 + i;
        #pragma unroll
        for (int j = 0; j < 4; ++j) {
            float v = acc[i][j] + bias[j];
            if (act) v = tanhf(v);
            C[(size_t)m * ldc + n0 + tx * 4 + j] = v;
        }
    }
}

__global__ void lstm_gate(const float* __restrict__ g,
                          float* __restrict__ h, float* __restrict__ c)
{
    const int i = blockIdx.x * blockDim.x + threadIdx.x;
    if (i >= BB * HH) return;
    const int b = i / HH, k = i % HH;
    const float* gb = g + (size_t)b * 4 * HH;
    const float gi = gb[k];
    const float gf = gb[HH + k];
    const float gg = gb[2 * HH + k];
    const float go = gb[3 * HH + k];
    const float si = 1.f / (1.f + expf(-gi));
    const float sf = 1.f / (1.f + expf(-gf));
    const float so = 1.f / (1.f + expf(-go));
    const float cn = sf * c[i] + si * tanhf(gg);
    c[i] = cn;
    h[i] = so * tanhf(cn);
}

// Legacy two-pass fp32 attention (fallback path only).
__global__ __launch_bounds__(256) void attn_kernel(
    const float* __restrict__ q, const float* __restrict__ enc,
    float* __restrict__ cross)
{
    const int b = blockIdx.x, tid = threadIdx.x;
    __shared__ float qs[ENCE];
    __shared__ float sc[SS];
    __shared__ float red[256];

    const float* qb = q + (size_t)b * ENCE;
    const float* eb = enc + (size_t)b * SS * ENCE;

    for (int e = tid; e < ENCE; e += 256) qs[e] = qb[e];
    __syncthreads();

    {
        const float* row = eb + (size_t)tid * ENCE;
        float a = 0.f;
        for (int e = 0; e < ENCE; e += 4) {
            const float4 ev = *(const float4*)&row[e];
            a += ev.x * qs[e] + ev.y * qs[e + 1] + ev.z * qs[e + 2] + ev.w * qs[e + 3];
        }
        sc[tid] = a;
    }
    __syncthreads();

    red[tid] = sc[tid];
    __syncthreads();
    for (int off = 128; off > 0; off >>= 1) {
        if (tid < off) red[tid] = fmaxf(red[tid], red[tid + off]);
        __syncthreads();
    }
    const float mx = red[0];
    __syncthreads();
    const float ex = expf(sc[tid] - mx);
    red[tid] = ex;
    __syncthreads();
    for (int off = 128; off > 0; off >>= 1) {
        if (tid < off) red[tid] += red[tid + off];
        __syncthreads();
    }
    const float inv = 1.f / red[0];
    __syncthreads();
    sc[tid] = ex * inv;
    __syncthreads();

    float4 acc = {0.f, 0.f, 0.f, 0.f};
    const int e0 = tid * 4;
    for (int s = 0; s < SS; ++s) {
        const float w = sc[s];
        const float4 ev = *(const float4*)&eb[(size_t)s * ENCE + e0];
        acc.x += w * ev.x; acc.y += w * ev.y; acc.z += w * ev.z; acc.w += w * ev.w;
    }
    *(float4*)&cross[(size_t)b * ENCE + e0] = acc;
}

// Single-pass flash-style fp32 attention: one block per b, online softmax,
// enc read ONCE per step. LDS: 16-row enc chunk (64 KB) + q (4 KB).
__global__ __launch_bounds__(256) void attn_flash(
    const float* __restrict__ q, const float* __restrict__ enc,
    float* __restrict__ cross)
{
    const int b = blockIdx.x, tid = threadIdx.x;
    __shared__ float qs[ENCE];
    __shared__ float es[16 * ENCE];     // 64 KB chunk
    __shared__ float sc[16];

    const float* qb = q + (size_t)b * ENCE;
    const float* eb = enc + (size_t)b * SS * ENCE;

    for (int e = tid * 4; e < ENCE; e += 1024)
        *(float4*)&qs[e] = *(const float4*)&qb[e];
    __syncthreads();

    const int sl  = tid >> 4;    // 0..15 : local row for score
    const int seg = tid & 15;    // 0..15 : column interleave group
    const int e0  = tid * 4;     // this thread's 4 output cols

    float m = -INFINITY, l = 0.f;
    float4 o = {0.f, 0.f, 0.f, 0.f};

    for (int s0 = 0; s0 < SS; s0 += 16) {
        // ---- stage 16 rows (fully coalesced float4) ----
        {
            const float* src = eb + (size_t)s0 * ENCE;
            #pragma unroll
            for (int i = 0; i < 16; ++i) {
                const int idx = tid * 4 + i * 1024;
                *(float4*)&es[idx] = *(const float4*)&src[idx];
            }
        }
        __syncthreads();

        // ---- scores: thread (sl,seg) sums cols {seg*4 + j*64} of row sl ----
        {
            float a = 0.f;
            const float* row = &es[sl * ENCE];
            #pragma unroll
            for (int j = 0; j < 16; ++j) {
                const int e = seg * 4 + j * 64;   // conflict-free interleave
                const float4 ev = *(const float4*)&row[e];
                const float4 qv = *(const float4*)&qs[e];
                a += ev.x * qv.x + ev.y * qv.y + ev.z * qv.z + ev.w * qv.w;
            }
            a += __shfl_xor(a, 1, 16);
            a += __shfl_xor(a, 2, 16);
            a += __shfl_xor(a, 4, 16);
            a += __shfl_xor(a, 8, 16);
            if (seg == 0) sc[sl] = a;
        }
        __syncthreads();

        // ---- online softmax update (redundant per-thread, no divergence) ----
        {
            float cm = sc[0];
            #pragma unroll
            for (int i = 1; i < 16; ++i) cm = fmaxf(cm, sc[i]);
            const float mn = fmaxf(m, cm);
            const float scale = expf(m - mn);
            o.x *= scale; o.y *= scale; o.z *= scale; o.w *= scale;
            l *= scale;
            float p[16];
            #pragma unroll
            for (int i = 0; i < 16; ++i) { p[i] = expf(sc[i] - mn); l += p[i]; }
            #pragma unroll
            for (int i = 0; i < 16; ++i) {
                const float4 ev = *(const float4*)&es[i * ENCE + e0];
                o.x += p[i] * ev.x; o.y += p[i] * ev.y;
                o.z += p[i] * ev.z; o.w += p[i] * ev.w;
            }
            m = mn;
        }
        __syncthreads();   // before next chunk overwrites es
    }

    const float inv = 1.f / l;
    float4 r = {o.x * inv, o.y * inv, o.z * inv, o.w * inv};
    *(float4*)&cross[(size_t)b * ENCE + e0] = r;
}

__global__ __launch_bounds__(256) void out_kernel(
    const float* __restrict__ lin, const float* __restrict__ Wout,
    const float* __restrict__ bout, float* __restrict__ tokens,
    float* __restrict__ logits, const int t)
{
    const int b = blockIdx.x, tid = threadIdx.x;
    __shared__ float ls[HH];
    __shared__ float vmax[256];
    __shared__ int   vidx[256];

    const float* lb = lin + (size_t)b * HH;
    for (int e = tid; e < HH; e += 256) ls[e] = lb[e];
    __syncthreads();

    float best = -INFINITY; int bi = 0;
    for (int n = tid; n < VV; n += 256) {
        const float* wr = Wout + (size_t)n * HH;
        float a = bout[n];
        for (int e = 0; e < HH; e += 4) {
            const float4 wv = *(const float4*)&wr[e];
            a += wv.x * ls[e] + wv.y * ls[e + 1] + wv.z * ls[e + 2] + wv.w * ls[e + 3];
        }
        logits[((size_t)b * TT + t) * VV + n] = a;
        if (a > best) { best = a; bi = n; }
    }
    vmax[tid] = best; vidx[tid] = bi;
    __syncthreads();
    for (int off = 128; off > 0; off >>= 1) {
        if (tid < off) {
            const float vo = vmax[tid + off]; const int io = vidx[tid + off];
            if (vo > vmax[tid] || (vo == vmax[tid] && io < vidx[tid])) {
                vmax[tid] = vo; vidx[tid] = io;
            }
        }
        __syncthreads();
    }
    if (tid == 0) tokens[(size_t)b * TT + t] = (float)vidx[0];
}

__global__ void gather_emb(const int* __restrict__ y,
                           const float* __restrict__ table,
                           float* __restrict__ emb, const int t)
{
    const int i = blockIdx.x * blockDim.x + threadIdx.x;
    if (i >= BB * EE) return;
    const int b = i / EE, e = i % EE;
    emb[i] = table[(size_t)y[(size_t)b * TT + t] * EE + e];
}

__global__ void scatter_init(const float* __restrict__ ini,
                             float* __restrict__ h0, float* __restrict__ h1,
                             float* __restrict__ c0, float* __restrict__ c1)
{
    const int i = blockIdx.x * blockDim.x + threadIdx.x;
    if (i >= BB * 4 * HH) return;
    const int b = i / (4 * HH), j = i % (4 * HH);
    const int i1 = j / (2 * HH);
    const int rem = j % (2 * HH);
    const int i2 = rem / HH;
    const int k = rem % HH;
    float* dst = (i1 == 0) ? (i2 == 0 ? h0 : h1) : (i2 == 0 ? c0 : c1);
    dst[(size_t)b * HH + k] = ini[i];
}

__global__ void zero_kernel(float* __restrict__ p, const int n)
{
    const int i = blockIdx.x * blockDim.x + threadIdx.x;
    if (i < n) p[i] = 0.f;
}

// ===========================================================================
// 3-split bf16 MFMA path (fp32-grade: missing terms ~2^-24)
// ===========================================================================
__global__ void conv_w3(const float* __restrict__ src, const int N, const int K,
                        unsigned short* __restrict__ dh,
                        unsigned short* __restrict__ dm,
                        unsigned short* __restrict__ dl,
                        const int dld, const int coff)
{
    const int total = N * K;
    for (int i = blockIdx.x * blockDim.x + threadIdx.x; i < total;
         i += gridDim.x * blockDim.x) {
        const int n = i / K, k = i - n * K;
        const float x = src[i];
        const unsigned short hb = f2b_hi(x);
        const float r1 = x - b2f(hb);
        const unsigned short mb = f2b_hi(r1);
        const float r2 = r1 - b2f(mb);
        const unsigned short lb = f2b_hi(r2);
        const size_t o = (size_t)n * dld + coff + k;
        dh[o] = hb; dm[o] = mb; dl[o] = lb;
    }
}

// Software-pipelined 3-split MFMA GEMM, split-K partials.
//   Cpart[p][M=256][N] = A[M, kbeg:kend] @ W[N, kbeg:kend]^T
// A: fp32 dual-source concat (col<K0 -> A0 else A1); if yidx!=null, A0 row
// indices come from yidx[(row)*TT+t] into table A0 (fused embedding gather).
// Pipeline: prologue-load tile 0; loop { barrier; LDS-write k; barrier;
// issue loads k+1; compute k } — global loads in flight under MFMA compute.
__global__ __launch_bounds__(256) void gemm_mfma6(
    const float* __restrict__ A0, const int lda0,
    const float* __restrict__ A1, const int lda1, const int K0,
    const int* __restrict__ yidx, const int t,
    const unsigned short* __restrict__ Wh, const unsigned short* __restrict__ Wm,
    const unsigned short* __restrict__ Wl,
    const int Kt, float* __restrict__ Cpart, const int N, const int chunk)
{
    __shared__ short Ah[64][40], Am[64][40], Al[64][40];
    __shared__ short Wsh[128][40], Wsm[128][40], Wsl[128][40];

    const int tid = threadIdx.x;
    const int n0 = blockIdx.x * 128;
    const int m0 = blockIdx.y * 64;
    const int p  = blockIdx.z;
    const int kbeg = p * chunk, kend = kbeg + chunk;

    const int lane = tid & 63, wave = tid >> 6;
    const int wm = wave >> 1, wn = wave & 1;
    const int l15 = lane & 15, lg = lane >> 4;

    const int ar = tid >> 2, ag = tid & 3;     // staging: row 0..63, k-grp 0..3

    // per-row A base pointers (fused gather if yidx given)
    const float* Abase0;
    if (yidx) Abase0 = A0 + (size_t)yidx[(size_t)(m0 + ar) * TT + t] * lda0;
    else      Abase0 = A0 + (size_t)(m0 + ar) * lda0;
    const float* Abase1 = A1 + (size_t)(m0 + ar) * lda1;
    const unsigned short* Wrow0 = (const unsigned short*)0;  // offsets computed inline

    f4v acc[2][4];
    #pragma unroll
    for (int i = 0; i < 2; ++i)
        #pragma unroll
        for (int j = 0; j < 4; ++j) acc[i][j] = (f4v){0.f, 0.f, 0.f, 0.f};

    float4 av0, av1;
    uint4 wh0, wm0, wl0, wh1, wm1, wl1;

    auto load_tile = [&](int kk_) {
        const int acol = kk_ + ag * 8;
        const float* Ap = (acol < K0) ? (Abase0 + acol) : (Abase1 + (acol - K0));
        av0 = *(const float4*)(Ap);
        av1 = *(const float4*)(Ap + 4);
        const size_t o0 = (size_t)(n0 + ar) * Kt + kk_ + ag * 8;
        const size_t o1 = o0 + (size_t)64 * Kt;
        wh0 = *(const uint4*)(Wh + o0);
        wm0 = *(const uint4*)(Wm + o0);
        wl0 = *(const uint4*)(Wl + o0);
        wh1 = *(const uint4*)(Wh + o1);
        wm1 = *(const uint4*)(Wm + o1);
        wl1 = *(const uint4*)(Wl + o1);
    };

    load_tile(kbeg);

    for (int kk = kbeg; kk < kend; kk += 32) {
        __syncthreads();   // previous iteration's fragment reads complete

        {   // A: split 8 floats -> hi/mid/lo bf16x8
            bf8v vh, vm, vl;
            const float xs[8] = {av0.x, av0.y, av0.z, av0.w,
                                 av1.x, av1.y, av1.z, av1.w};
            #pragma unroll
            for (int j = 0; j < 8; ++j) {
                const unsigned short hb = f2b_hi(xs[j]);
                const float r1 = xs[j] - b2f(hb);
                const unsigned short mb = f2b_hi(r1);
                const float r2 = r1 - b2f(mb);
                vh[j] = (short)hb;
                vm[j] = (short)mb;
                vl[j] = (short)f2b_hi(r2);
            }
            *(bf8v*)&Ah[ar][ag * 8] = vh;
            *(bf8v*)&Am[ar][ag * 8] = vm;
            *(bf8v*)&Al[ar][ag * 8] = vl;
        }
        *(uint4*)&Wsh[ar][ag * 8] = wh0;
        *(uint4*)&Wsm[ar][ag * 8] = wm0;
        *(uint4*)&Wsl[ar][ag * 8] = wl0;
        *(uint4*)&Wsh[64 + ar][ag * 8] = wh1;
        *(uint4*)&Wsm[64 + ar][ag * 8] = wm1;
        *(uint4*)&Wsl[64 + ar][ag * 8] = wl1;

        __syncthreads();

        if (kk + 32 < kend) load_tile(kk + 32);   // in flight under compute

        bf8v afh[2], afm[2], afl[2];
        #pragma unroll
        for (int fr = 0; fr < 2; ++fr) {
            const int r = wm * 32 + fr * 16 + l15;
            afh[fr] = *(const bf8v*)&Ah[r][lg * 8];
            afm[fr] = *(const bf8v*)&Am[r][lg * 8];
            afl[fr] = *(const bf8v*)&Al[r][lg * 8];
        }
        #pragma unroll
        for (int fn = 0; fn < 4; ++fn) {
            const int r = wn * 64 + fn * 16 + l15;
            const bf8v wfh = *(const bf8v*)&Wsh[r][lg * 8];
            const bf8v wfm = *(const bf8v*)&Wsm[r][lg * 8];
            const bf8v wfl = *(const bf8v*)&Wsl[r][lg * 8];
            #pragma unroll
            for (int fr = 0; fr < 2; ++fr) {
                acc[fr][fn] = __builtin_amdgcn_mfma_f32_16x16x32_bf16(
                    afl[fr], wfh, acc[fr][fn], 0, 0, 0);
                acc[fr][fn] = __builtin_amdgcn_mfma_f32_16x16x32_bf16(
                    afh[fr], wfl, acc[fr][fn], 0, 0, 0);
                acc[fr][fn] = __builtin_amdgcn_mfma_f32_16x16x32_bf16(
                    afm[fr], wfm, acc[fr][fn], 0, 0, 0);
                acc[fr][fn] = __builtin_amdgcn_mfma_f32_16x16x32_bf16(
                    afm[fr], wfh, acc[fr][fn], 0, 0, 0);
                acc[fr][fn] = __builtin_amdgcn_mfma_f32_16x16x32_bf16(
                    afh[fr], wfm, acc[fr][fn], 0, 0, 0);
                acc[fr][fn] = __builtin_amdgcn_mfma_f32_16x16x32_bf16(
                    afh[fr], wfh, acc[fr][fn], 0, 0, 0);
            }
        }
    }

    // epilogue: C/D layout col=lane&15, row=(lane>>4)*4+reg
    float* slab = Cpart + (size_t)p * BB * N;
    #pragma unroll
    for (int fr = 0; fr < 2; ++fr) {
        const int row0 = m0 + wm * 32 + fr * 16 + lg * 4;
        #pragma unroll
        for (int fn = 0; fn < 4; ++fn) {
            const int col = n0 + wn * 64 + fn * 16 + l15;
            #pragma unroll
            for (int j = 0; j < 4; ++j)
                slab[(size_t)(row0 + j) * N + col] = acc[fr][fn][j];
        }
    }
}

// split-K reduce + bias + tanh
__global__ void ep_tanh(const float* __restrict__ part, const int P,
                        const float* __restrict__ bias, float* __restrict__ dst,
                        const int total, const int N)
{
    for (int i = blockIdx.x * blockDim.x + threadIdx.x; i < total;
         i += gridDim.x * blockDim.x) {
        const int n = i % N;
        float s = bias[n];
        for (int p = 0; p < P; ++p) s += part[(size_t)p * total + i];
        dst[i] = tanhf(s);
    }
}

// split-K reduce + biases + LSTM gate pointwise
__global__ void ep_gate(const float* __restrict__ part, const int P,
                        const float* __restrict__ bih, const float* __restrict__ bhh,
                        float* __restrict__ h, float* __restrict__ c)
{
    const int i = blockIdx.x * blockDim.x + threadIdx.x;
    if (i >= BB * HH) return;
    const int b = i >> 10, k = i & (HH - 1);
    const size_t base = (size_t)b * 4 * HH;
    float gi = bih[k] + bhh[k];
    float gf = bih[HH + k] + bhh[HH + k];
    float gg = bih[2 * HH + k] + bhh[2 * HH + k];
    float go = bih[3 * HH + k] + bhh[3 * HH + k];
    for (int p = 0; p < P; ++p) {
        const float* gp = part + (size_t)p * BB * 4 * HH + base;
        gi += gp[k]; gf += gp[HH + k]; gg += gp[2 * HH + k]; go += gp[3 * HH + k];
    }
    const float si = 1.f / (1.f + expf(-gi));
    const float sf = 1.f / (1.f + expf(-gf));
    const float so = 1.f / (1.f + expf(-go));
    const float cn = sf * c[i] + si * tanhf(gg);
    c[i] = cn;
    h[i] = so * tanhf(cn);
}

// ===========================================================================
extern "C" void kernel_launch(void* const* d_in, const int* in_sizes, int n_in,
                              void* d_out, int out_size, void* d_ws, size_t ws_size,
                              hipStream_t stream)
{
    const int*   y         = (const int*)  d_in[0];
    const float* enc       = (const float*)d_in[1];
    const float* esum      = (const float*)d_in[2];
    const float* emb_table = (const float*)d_in[3];
    const float* W_init    = (const float*)d_in[4];
    const float* b_init    = (const float*)d_in[5];
    const float* W_ci      = (const float*)d_in[6];
    const float* b_ci      = (const float*)d_in[7];
    const float* Wih0      = (const float*)d_in[8];
    const float* Whh0      = (const float*)d_in[9];
    const float* bih0      = (const float*)d_in[10];
    const float* bhh0      = (const float*)d_in[11];
    const float* Wih1      = (const float*)d_in[12];
    const float* Whh1      = (const float*)d_in[13];
    const float* bih1      = (const float*)d_in[14];
    const float* bhh1      = (const float*)d_in[15];
    const float* Wq        = (const float*)d_in[16];
    const float* bq        = (const float*)d_in[17];
    const float* Wco       = (const float*)d_in[18];
    const float* bco       = (const float*)d_in[19];
    const float* Wout      = (const float*)d_in[20];
    const float* bout      = (const float*)d_in[21];

    float* out    = (float*)d_out;
    float* tokens = out;
    float* logits = out + (size_t)BB * TT;

    // ---- workspace carve ----
    char* wsb = (char*)d_ws;
    size_t off = 0;
    auto alloc = [&](size_t bytes) -> char* {
        char* p = wsb + off;
        off = (off + bytes + 255) & ~(size_t)255;
        return p;
    };
    float* h0    = (float*)alloc((size_t)BB * HH * 4);
    float* h1    = (float*)alloc((size_t)BB * HH * 4);
    float* c0    = (float*)alloc((size_t)BB * HH * 4);
    float* c1    = (float*)alloc((size_t)BB * HH * 4);
    float* cross = (float*)alloc((size_t)BB * ENCE * 4);
    float* xbuf  = (float*)alloc((size_t)BB * EE * 4);
    float* embb  = (float*)alloc((size_t)BB * EE * 4);
    float* gbuf  = (float*)alloc((size_t)BB * 4 * HH * 4);
    float* qbuf  = (float*)alloc((size_t)BB * ENCE * 4);

    float* part = (float*)alloc((size_t)4 * BB * 4 * HH * 4);   // 16 MiB

    unsigned short *ci_s[3], *g0_s[3], *g1_s[3], *wq_s[3], *wc_s[3];
    for (int s = 0; s < 3; ++s) ci_s[s] = (unsigned short*)alloc((size_t)EE * 1536 * 2);
    for (int s = 0; s < 3; ++s) g0_s[s] = (unsigned short*)alloc((size_t)4 * HH * 1536 * 2);
    for (int s = 0; s < 3; ++s) g1_s[s] = (unsigned short*)alloc((size_t)4 * HH * 2048 * 2);
    for (int s = 0; s < 3; ++s) wq_s[s] = (unsigned short*)alloc((size_t)ENCE * 2048 * 2);
    for (int s = 0; s < 3; ++s) wc_s[s] = (unsigned short*)alloc((size_t)HH * 2048 * 2);
    const size_t need_mfma = off;

    const int mfma_ok = (ws_size >= need_mfma);

    const dim3 thr(256);

    // ---- decoder_init (fp32, once) ----
    gemm2<<<dim3(4 * HH / 64, BB / 64), thr, 0, stream>>>(
        esum, W_init, SUME, SUME, SUME,
        nullptr, nullptr, SUME, 0, 0,
        b_init, nullptr, gbuf, 4 * HH, 1);
    scatter_init<<<dim3(BB * 4 * HH / 256), thr, 0, stream>>>(gbuf, h0, h1, c0, c1);
    zero_kernel<<<dim3(BB * ENCE / 256), thr, 0, stream>>>(cross, BB * ENCE);

    if (!mfma_ok) {
        for (int t = 0; t < TT; ++t) {
            gather_emb<<<dim3(BB * EE / 256), thr, 0, stream>>>(y, emb_table, embb, t);
            gemm2<<<dim3(EE / 64, BB / 64), thr, 0, stream>>>(
                embb, W_ci, EE, EE, EE + ENCE,
                cross, W_ci + EE, EE + ENCE, ENCE, EE + ENCE,
                b_ci, nullptr, xbuf, EE, 1);
            gemm2<<<dim3(4 * HH / 64, BB / 64), thr, 0, stream>>>(
                xbuf, Wih0, EE, EE, EE,
                h0, Whh0, EE + HH, HH, HH,
                bih0, bhh0, gbuf, 4 * HH, 0);
            lstm_gate<<<dim3(BB * HH / 256), thr, 0, stream>>>(gbuf, h0, c0);
            gemm2<<<dim3(4 * HH / 64, BB / 64), thr, 0, stream>>>(
                h0, Wih1, HH, HH, HH,
                h1, Whh1, 2 * HH, HH, HH,
                bih1, bhh1, gbuf, 4 * HH, 0);
            lstm_gate<<<dim3(BB * HH / 256), thr, 0, stream>>>(gbuf, h1, c1);
            gemm2<<<dim3(ENCE / 64, BB / 64), thr, 0, stream>>>(
                h1, Wq, HH, HH, 2 * HH,
                c1, Wq + HH, 2 * HH, HH, 2 * HH,
                bq, nullptr, qbuf, ENCE, 1);
            attn_kernel<<<dim3(BB), thr, 0, stream>>>(qbuf, enc, cross);
            gemm2<<<dim3(HH / 64, BB / 64), thr, 0, stream>>>(
                h1, Wco, HH, HH, ENCE + HH,
                cross, Wco + HH, ENCE + HH, ENCE, ENCE + HH,
                bco, nullptr, qbuf, HH, 1);
            out_kernel<<<dim3(BB), thr, 0, stream>>>(qbuf, Wout, bout, tokens, logits, t);
        }
        return;
    }

    // ---- one-time weight 3-splits ----
    const dim3 cg(4096);
    conv_w3<<<cg, thr, 0, stream>>>(W_ci, EE, EE + ENCE, ci_s[0], ci_s[1], ci_s[2], 1536, 0);
    conv_w3<<<cg, thr, 0, stream>>>(Wih0, 4 * HH, EE, g0_s[0], g0_s[1], g0_s[2], 1536, 0);
    conv_w3<<<cg, thr, 0, stream>>>(Whh0, 4 * HH, HH, g0_s[0], g0_s[1], g0_s[2], 1536, EE);
    conv_w3<<<cg, thr, 0, stream>>>(Wih1, 4 * HH, HH, g1_s[0], g1_s[1], g1_s[2], 2048, 0);
    conv_w3<<<cg, thr, 0, stream>>>(Whh1, 4 * HH, HH, g1_s[0], g1_s[1], g1_s[2], 2048, HH);
    conv_w3<<<cg, thr, 0, stream>>>(Wq, ENCE, 2 * HH, wq_s[0], wq_s[1], wq_s[2], 2048, 0);
    conv_w3<<<cg, thr, 0, stream>>>(Wco, HH, ENCE + HH, wc_s[0], wc_s[1], wc_s[2], 2048, 0);

    auto gemmS = [&](const float* A0, int lda0, const float* A1, int lda1, int K0,
                     const int* yi, int t_, unsigned short* const* Ws,
                     int Kt, int N, int P) {
        gemm_mfma6<<<dim3(N / 128, BB / 64, P), thr, 0, stream>>>(
            A0, lda0, A1, lda1, K0, yi, t_, Ws[0], Ws[1], Ws[2], Kt, part, N, Kt / P);
    };

    for (int t = 0; t < TT; ++t) {
        // x = tanh([emb_table[y[:,t]] | cross] @ Wci^T + b_ci)  (fused gather)
        gemmS(emb_table, EE, cross, ENCE, EE, y, t, ci_s, 1536, EE, 16);
        ep_tanh<<<dim3(512), thr, 0, stream>>>(part, 16, b_ci, xbuf, BB * EE, EE);

        // layer0 gates
        gemmS(xbuf, EE, h0, HH, EE, nullptr, 0, g0_s, 1536, 4 * HH, 4);
        ep_gate<<<dim3(BB * HH / 256), thr, 0, stream>>>(part, 4, bih0, bhh0, h0, c0);

        // layer1 gates
        gemmS(h0, HH, h1, HH, HH, nullptr, 0, g1_s, 2048, 4 * HH, 4);
        ep_gate<<<dim3(BB * HH / 256), thr, 0, stream>>>(part, 4, bih1, bhh1, h1, c1);

        // q = tanh([h1 | c1] @ Wq^T + bq)
        gemmS(h1, HH, c1, HH, HH, nullptr, 0, wq_s, 2048, ENCE, 8);
        ep_tanh<<<dim3(1024), thr, 0, stream>>>(part, 8, bq, qbuf, BB * ENCE, ENCE);

        // attention -> cross (single-pass flash, fp32)
        attn_flash<<<dim3(BB), thr, 0, stream>>>(qbuf, enc, cross);

        // lin = tanh([h1 | cross] @ Wco^T + bco)
        gemmS(h1, HH, cross, ENCE, HH, nullptr, 0, wc_s, 2048, HH, 8);
        ep_tanh<<<dim3(1024), thr, 0, stream>>>(part, 8, bco, qbuf, BB * HH, HH);

        // logits + argmax
        out_kernel<<<dim3(BB), thr, 0, stream>>>(qbuf, Wout, bout, tokens, logits, t);
    }
}

// Round 5
// 17316.328 us; speedup vs baseline: 2.7058x; 1.0333x over previous
//
#include <hip/hip_runtime.h>
#include <math.h>

// Problem constants (match reference)
#define BB   256   // batch
#define TT   64    // timesteps
#define SS   256   // encoder seq len
#define VV   512   // vocab
#define EE   512   // embed dim
#define HH   1024  // hidden
#define ENCE 1024  // encoder dim
#define SUME 2048  // summary dim

typedef __attribute__((ext_vector_type(8))) _Float16 h8v;  // 8 fp16 (4 VGPR)
typedef __attribute__((ext_vector_type(4))) float f4v;

// fp32 -> fp16 (hi, lo*2^12) split. Reconstruction: x ~= h + l * 2^-12,
// |err| <= 2^-24 |x|. Scaling by 4096 keeps l in fp16 normal range.
__device__ __forceinline__ void split16(float x, _Float16& h, _Float16& l) {
    h = (_Float16)x;
    l = (_Float16)((x - (float)h) * 4096.0f);
}

// ===========================================================================
// LEGACY fp32 path (known-good): decoder_init always; full fallback if ws
// too small.
// ===========================================================================
__global__ __launch_bounds__(256) void gemm2(
    const float* __restrict__ A0, const float* __restrict__ W0, const int K0,
    const int lda0, const int ldw0,
    const float* __restrict__ A1, const float* __restrict__ W1, const int Ktot,
    const int lda1, const int ldw1,
    const float* __restrict__ b0, const float* __restrict__ b1,
    float* __restrict__ C, const int ldc, const int act)
{
    __shared__ float As[16][68];
    __shared__ float Ws[16][68];

    const int tid = threadIdx.x;
    const int n0  = blockIdx.x * 64;
    const int m0  = blockIdx.y * 64;
    const int lr  = tid >> 2;
    const int lc  = (tid & 3) << 2;
    const int tx  = tid & 15;
    const int ty  = tid >> 4;

    float acc[4][4] = {{0.f}};

    for (int k0 = 0; k0 < Ktot; k0 += 16) {
        const float* A; const float* W; int lda, ldw, kk;
        if (k0 < K0) { A = A0; W = W0; lda = lda0; ldw = ldw0; kk = k0; }
        else         { A = A1; W = W1; lda = lda1; ldw = ldw1; kk = k0 - K0; }

        const float4 av = *(const float4*)(A + (size_t)(m0 + lr) * lda + kk + lc);
        const float4 wv = *(const float4*)(W + (size_t)(n0 + lr) * ldw + kk + lc);

        __syncthreads();
        As[lc + 0][lr] = av.x; As[lc + 1][lr] = av.y;
        As[lc + 2][lr] = av.z; As[lc + 3][lr] = av.w;
        Ws[lc + 0][lr] = wv.x; Ws[lc + 1][lr] = wv.y;
        Ws[lc + 2][lr] = wv.z; Ws[lc + 3][lr] = wv.w;
        __syncthreads();

        #pragma unroll
        for (int p = 0; p < 16; ++p) {
            const float4 a4 = *(const float4*)&As[p][ty * 4];
            const float4 w4 = *(const float4*)&Ws[p][tx * 4];
            acc[0][0] += a4.x * w4.x; acc[0][1] += a4.x * w4.y;
            acc[0][2] += a4.x * w4.z; acc[0][3] += a4.x * w4.w;
            acc[1][0] += a4.y * w4.x; acc[1][1] += a4.y * w4.y;
            acc[1][2] += a4.y * w4.z; acc[1][3] += a4.y * w4.w;
            acc[2][0] += a4.z * w4.x; acc[2][1] += a4.z * w4.y;
            acc[2][2] += a4.z * w4.z; acc[2][3] += a4.z * w4.w;
            acc[3][0] += a4.w * w4.x; acc[3][1] += a4.w * w4.y;
            acc[3][2] += a4.w * w4.z; acc[3][3] += a4.w * w4.w;
        }
    }

    float bias[4];
    #pragma unroll
    for (int j = 0; j < 4; ++j) {
        const int n = n0 + tx * 4 + j;
        bias[j] = b0[n] + (b1 ? b1[n] : 0.f);
    }
    #pragma unroll
    for (int i = 0; i < 4; ++i) {
        const int m = m0 + ty * 4 + i;
        #pragma unroll
        for (int j = 0; j < 4; ++j) {
            float v = acc[i][j] + bias[j];
            if (act) v = tanhf(v);
            C[(size_t)m * ldc + n0 + tx * 4 + j] = v;
        }
    }
}

__global__ void lstm_gate(const float* __restrict__ g,
                          float* __restrict__ h, float* __restrict__ c)
{
    const int i = blockIdx.x * blockDim.x + threadIdx.x;
    if (i >= BB * HH) return;
    const int b = i / HH, k = i % HH;
    const float* gb = g + (size_t)b * 4 * HH;
    const float gi = gb[k];
    const float gf = gb[HH + k];
    const float gg = gb[2 * HH + k];
    const float go = gb[3 * HH + k];
    const float si = 1.f / (1.f + expf(-gi));
    const float sf = 1.f / (1.f + expf(-gf));
    const float so = 1.f / (1.f + expf(-go));
    const float cn = sf * c[i] + si * tanhf(gg);
    c[i] = cn;
    h[i] = so * tanhf(cn);
}

// Legacy two-pass fp32 attention (fallback path only).
__global__ __launch_bounds__(256) void attn_kernel(
    const float* __restrict__ q, const float* __restrict__ enc,
    float* __restrict__ cross)
{
    const int b = blockIdx.x, tid = threadIdx.x;
    __shared__ float qs[ENCE];
    __shared__ float sc[SS];
    __shared__ float red[256];

    const float* qb = q + (size_t)b * ENCE;
    const float* eb = enc + (size_t)b * SS * ENCE;

    for (int e = tid; e < ENCE; e += 256) qs[e] = qb[e];
    __syncthreads();

    {
        const float* row = eb + (size_t)tid * ENCE;
        float a = 0.f;
        for (int e = 0; e < ENCE; e += 4) {
            const float4 ev = *(const float4*)&row[e];
            a += ev.x * qs[e] + ev.y * qs[e + 1] + ev.z * qs[e + 2] + ev.w * qs[e + 3];
        }
        sc[tid] = a;
    }
    __syncthreads();

    red[tid] = sc[tid];
    __syncthreads();
    for (int off = 128; off > 0; off >>= 1) {
        if (tid < off) red[tid] = fmaxf(red[tid], red[tid + off]);
        __syncthreads();
    }
    const float mx = red[0];
    __syncthreads();
    const float ex = expf(sc[tid] - mx);
    red[tid] = ex;
    __syncthreads();
    for (int off = 128; off > 0; off >>= 1) {
        if (tid < off) red[tid] += red[tid + off];
        __syncthreads();
    }
    const float inv = 1.f / red[0];
    __syncthreads();
    sc[tid] = ex * inv;
    __syncthreads();

    float4 acc = {0.f, 0.f, 0.f, 0.f};
    const int e0 = tid * 4;
    for (int s = 0; s < SS; ++s) {
        const float w = sc[s];
        const float4 ev = *(const float4*)&eb[(size_t)s * ENCE + e0];
        acc.x += w * ev.x; acc.y += w * ev.y; acc.z += w * ev.z; acc.w += w * ev.w;
    }
    *(float4*)&cross[(size_t)b * ENCE + e0] = acc;
}

// Single-pass flash-style fp32 attention + fp16-split emission of cross.
__global__ __launch_bounds__(256) void attn_flash(
    const float* __restrict__ q, const float* __restrict__ enc,
    float* __restrict__ cross,
    _Float16* __restrict__ crh, _Float16* __restrict__ crl)
{
    const int b = blockIdx.x, tid = threadIdx.x;
    __shared__ float qs[ENCE];
    __shared__ float es[16 * ENCE];     // 64 KB chunk
    __shared__ float sc[16];

    const float* qb = q + (size_t)b * ENCE;
    const float* eb = enc + (size_t)b * SS * ENCE;

    for (int e = tid * 4; e < ENCE; e += 1024)
        *(float4*)&qs[e] = *(const float4*)&qb[e];
    __syncthreads();

    const int sl  = tid >> 4;    // 0..15 : local row for score
    const int seg = tid & 15;    // 0..15 : column interleave group
    const int e0  = tid * 4;     // this thread's 4 output cols

    float m = -INFINITY, l = 0.f;
    float4 o = {0.f, 0.f, 0.f, 0.f};

    for (int s0 = 0; s0 < SS; s0 += 16) {
        {
            const float* src = eb + (size_t)s0 * ENCE;
            #pragma unroll
            for (int i = 0; i < 16; ++i) {
                const int idx = tid * 4 + i * 1024;
                *(float4*)&es[idx] = *(const float4*)&src[idx];
            }
        }
        __syncthreads();

        {
            float a = 0.f;
            const float* row = &es[sl * ENCE];
            #pragma unroll
            for (int j = 0; j < 16; ++j) {
                const int e = seg * 4 + j * 64;
                const float4 ev = *(const float4*)&row[e];
                const float4 qv = *(const float4*)&qs[e];
                a += ev.x * qv.x + ev.y * qv.y + ev.z * qv.z + ev.w * qv.w;
            }
            a += __shfl_xor(a, 1, 16);
            a += __shfl_xor(a, 2, 16);
            a += __shfl_xor(a, 4, 16);
            a += __shfl_xor(a, 8, 16);
            if (seg == 0) sc[sl] = a;
        }
        __syncthreads();

        {
            float cm = sc[0];
            #pragma unroll
            for (int i = 1; i < 16; ++i) cm = fmaxf(cm, sc[i]);
            const float mn = fmaxf(m, cm);
            const float scale = expf(m - mn);
            o.x *= scale; o.y *= scale; o.z *= scale; o.w *= scale;
            l *= scale;
            float p[16];
            #pragma unroll
            for (int i = 0; i < 16; ++i) { p[i] = expf(sc[i] - mn); l += p[i]; }
            #pragma unroll
            for (int i = 0; i < 16; ++i) {
                const float4 ev = *(const float4*)&es[i * ENCE + e0];
                o.x += p[i] * ev.x; o.y += p[i] * ev.y;
                o.z += p[i] * ev.z; o.w += p[i] * ev.w;
            }
            m = mn;
        }
        __syncthreads();
    }

    const float inv = 1.f / l;
    const float4 r = {o.x * inv, o.y * inv, o.z * inv, o.w * inv};
    *(float4*)&cross[(size_t)b * ENCE + e0] = r;

    // fp16 split emission (8B stores, coalesced)
    _Float16 h4[4], l4[4];
    split16(r.x, h4[0], l4[0]); split16(r.y, h4[1], l4[1]);
    split16(r.z, h4[2], l4[2]); split16(r.w, h4[3], l4[3]);
    *(uint2*)&crh[(size_t)b * ENCE + e0] = *(uint2*)h4;
    *(uint2*)&crl[(size_t)b * ENCE + e0] = *(uint2*)l4;
}

__global__ __launch_bounds__(256) void out_kernel(
    const float* __restrict__ lin, const float* __restrict__ Wout,
    const float* __restrict__ bout, float* __restrict__ tokens,
    float* __restrict__ logits, const int t)
{
    const int b = blockIdx.x, tid = threadIdx.x;
    __shared__ float ls[HH];
    __shared__ float vmax[256];
    __shared__ int   vidx[256];

    const float* lb = lin + (size_t)b * HH;
    for (int e = tid; e < HH; e += 256) ls[e] = lb[e];
    __syncthreads();

    float best = -INFINITY; int bi = 0;
    for (int n = tid; n < VV; n += 256) {
        const float* wr = Wout + (size_t)n * HH;
        float a = bout[n];
        for (int e = 0; e < HH; e += 4) {
            const float4 wv = *(const float4*)&wr[e];
            a += wv.x * ls[e] + wv.y * ls[e + 1] + wv.z * ls[e + 2] + wv.w * ls[e + 3];
        }
        logits[((size_t)b * TT + t) * VV + n] = a;
        if (a > best) { best = a; bi = n; }
    }
    vmax[tid] = best; vidx[tid] = bi;
    __syncthreads();
    for (int off = 128; off > 0; off >>= 1) {
        if (tid < off) {
            const float vo = vmax[tid + off]; const int io = vidx[tid + off];
            if (vo > vmax[tid] || (vo == vmax[tid] && io < vidx[tid])) {
                vmax[tid] = vo; vidx[tid] = io;
            }
        }
        __syncthreads();
    }
    if (tid == 0) tokens[(size_t)b * TT + t] = (float)vidx[0];
}

__global__ void gather_emb(const int* __restrict__ y,
                           const float* __restrict__ table,
                           float* __restrict__ emb, const int t)
{
    const int i = blockIdx.x * blockDim.x + threadIdx.x;
    if (i >= BB * EE) return;
    const int b = i / EE, e = i % EE;
    emb[i] = table[(size_t)y[(size_t)b * TT + t] * EE + e];
}

// gather + fp16 split (MFMA path)
__global__ void gather_split(const int* __restrict__ y,
                             const float* __restrict__ table,
                             _Float16* __restrict__ eh, _Float16* __restrict__ el,
                             const int t)
{
    const int i = blockIdx.x * blockDim.x + threadIdx.x;
    if (i >= BB * EE) return;
    const int b = i >> 9, e = i & (EE - 1);
    const float x = table[(size_t)y[(size_t)b * TT + t] * EE + e];
    split16(x, eh[i], el[i]);
}

// init scatter + optional fp16 splits for h0, h1, c1
__global__ void scatter_init_s(const float* __restrict__ ini,
                               float* __restrict__ h0, float* __restrict__ h1,
                               float* __restrict__ c0, float* __restrict__ c1,
                               _Float16* __restrict__ h0h, _Float16* __restrict__ h0l,
                               _Float16* __restrict__ h1h, _Float16* __restrict__ h1l,
                               _Float16* __restrict__ c1h, _Float16* __restrict__ c1l)
{
    const int i = blockIdx.x * blockDim.x + threadIdx.x;
    if (i >= BB * 4 * HH) return;
    const int b = i / (4 * HH), j = i % (4 * HH);
    const int i1 = j / (2 * HH);
    const int rem = j % (2 * HH);
    const int i2 = rem / HH;
    const int k = rem % HH;
    const float v = ini[i];
    const size_t o = (size_t)b * HH + k;
    float* dst = (i1 == 0) ? (i2 == 0 ? h0 : h1) : (i2 == 0 ? c0 : c1);
    dst[o] = v;
    if (h0h) {
        if (i1 == 0) {
            _Float16 h, l; split16(v, h, l);
            if (i2 == 0) { h0h[o] = h; h0l[o] = l; }
            else         { h1h[o] = h; h1l[o] = l; }
        } else if (i2 == 1) {
            _Float16 h, l; split16(v, h, l);
            c1h[o] = h; c1l[o] = l;
        }
    }
}

__global__ void zero_kernel(float* __restrict__ p, const int n)
{
    const int i = blockIdx.x * blockDim.x + threadIdx.x;
    if (i < n) p[i] = 0.f;
}

// ===========================================================================
// fp16 2-split MFMA path: 3 passes, 2 accumulators, fp32-grade (~2^-24).
// ===========================================================================

// fp32 weights -> fp16 (hi, lo*2^12), packed into column slice of [N][dld].
__global__ void conv_w2(const float* __restrict__ src, const int N, const int K,
                        _Float16* __restrict__ dh, _Float16* __restrict__ dl,
                        const int dld, const int coff)
{
    const int total = N * K;
    for (int i = blockIdx.x * blockDim.x + threadIdx.x; i < total;
         i += gridDim.x * blockDim.x) {
        const int n = i / K, k = i - n * K;
        const size_t o = (size_t)n * dld + coff + k;
        split16(src[i], dh[o], dl[o]);
    }
}

// Software-pipelined fp16-split MFMA GEMM, split-K partials:
//   Cpart[p][M=256][N] = A[M, kbeg:kend] @ W[N, kbeg:kend]^T
// A pre-split (h + 2^-12 l) fp16, dual-source concat (col<K0 -> A0 else A1).
// 3 MFMA passes: h*wh -> accm;  h*wl, l*wh -> accc;  out = accm + 2^-12 accc.
// Block: 256 thr = 4 waves (2m x 2n), tile 64x128, BK=32.
// Grid: (N/128, 256/64, P), chunk = Kt/P (multiple of 32).
__global__ __launch_bounds__(256) void gemm_f16(
    const _Float16* __restrict__ A0h, const _Float16* __restrict__ A0l, const int lda0,
    const _Float16* __restrict__ A1h, const _Float16* __restrict__ A1l, const int lda1,
    const int K0,
    const _Float16* __restrict__ Wh, const _Float16* __restrict__ Wl,
    const int Kt, float* __restrict__ Cpart, const int N, const int chunk)
{
    __shared__ _Float16 Ash[64][40], Asl[64][40];
    __shared__ _Float16 Wsh[128][40], Wsl[128][40];

    const int tid = threadIdx.x;
    const int n0 = blockIdx.x * 128;
    const int m0 = blockIdx.y * 64;
    const int p  = blockIdx.z;
    const int kbeg = p * chunk, kend = kbeg + chunk;

    const int lane = tid & 63, wave = tid >> 6;
    const int wm = wave >> 1, wn = wave & 1;
    const int l15 = lane & 15, lg = lane >> 4;

    const int ar = tid >> 2, ag = tid & 3;     // staging: row 0..63, k-grp 0..3

    f4v accm[2][4], accc[2][4];
    #pragma unroll
    for (int i = 0; i < 2; ++i)
        #pragma unroll
        for (int j = 0; j < 4; ++j) {
            accm[i][j] = (f4v){0.f, 0.f, 0.f, 0.f};
            accc[i][j] = (f4v){0.f, 0.f, 0.f, 0.f};
        }

    uint4 avh, avl, wh0, wl0, wh1, wl1;

    auto load_tile = [&](int kk_) {
        const int col = kk_ + ag * 8;
        if (col < K0) {
            const size_t o = (size_t)(m0 + ar) * lda0 + col;
            avh = *(const uint4*)(A0h + o);
            avl = *(const uint4*)(A0l + o);
        } else {
            const size_t o = (size_t)(m0 + ar) * lda1 + (col - K0);
            avh = *(const uint4*)(A1h + o);
            avl = *(const uint4*)(A1l + o);
        }
        const size_t o0 = (size_t)(n0 + ar) * Kt + kk_ + ag * 8;
        const size_t o1 = o0 + (size_t)64 * Kt;
        wh0 = *(const uint4*)(Wh + o0);
        wl0 = *(const uint4*)(Wl + o0);
        wh1 = *(const uint4*)(Wh + o1);
        wl1 = *(const uint4*)(Wl + o1);
    };

    load_tile(kbeg);

    for (int kk = kbeg; kk < kend; kk += 32) {
        __syncthreads();   // previous iteration's fragment reads complete

        *(uint4*)&Ash[ar][ag * 8] = avh;
        *(uint4*)&Asl[ar][ag * 8] = avl;
        *(uint4*)&Wsh[ar][ag * 8] = wh0;
        *(uint4*)&Wsl[ar][ag * 8] = wl0;
        *(uint4*)&Wsh[64 + ar][ag * 8] = wh1;
        *(uint4*)&Wsl[64 + ar][ag * 8] = wl1;

        __syncthreads();

        if (kk + 32 < kend) load_tile(kk + 32);   // in flight under compute

        h8v afh[2], afl[2];
        #pragma unroll
        for (int fr = 0; fr < 2; ++fr) {
            const int r = wm * 32 + fr * 16 + l15;
            afh[fr] = *(const h8v*)&Ash[r][lg * 8];
            afl[fr] = *(const h8v*)&Asl[r][lg * 8];
        }
        #pragma unroll
        for (int fn = 0; fn < 4; ++fn) {
            const int r = wn * 64 + fn * 16 + l15;
            const h8v wfh = *(const h8v*)&Wsh[r][lg * 8];
            const h8v wfl = *(const h8v*)&Wsl[r][lg * 8];
            #pragma unroll
            for (int fr = 0; fr < 2; ++fr) {
                accm[fr][fn] = __builtin_amdgcn_mfma_f32_16x16x32_f16(
                    afh[fr], wfh, accm[fr][fn], 0, 0, 0);
                accc[fr][fn] = __builtin_amdgcn_mfma_f32_16x16x32_f16(
                    afh[fr], wfl, accc[fr][fn], 0, 0, 0);
                accc[fr][fn] = __builtin_amdgcn_mfma_f32_16x16x32_f16(
                    afl[fr], wfh, accc[fr][fn], 0, 0, 0);
            }
        }
    }

    // epilogue: out = accm + 2^-12 * accc; C/D layout col=lane&15,
    // row=(lane>>4)*4+reg
    const float s12 = 0.000244140625f;  // 2^-12
    float* slab = Cpart + (size_t)p * BB * N;
    #pragma unroll
    for (int fr = 0; fr < 2; ++fr) {
        const int row0 = m0 + wm * 32 + fr * 16 + lg * 4;
        #pragma unroll
        for (int fn = 0; fn < 4; ++fn) {
            const int col = n0 + wn * 64 + fn * 16 + l15;
            #pragma unroll
            for (int j = 0; j < 4; ++j)
                slab[(size_t)(row0 + j) * N + col] =
                    accm[fr][fn][j] + s12 * accc[fr][fn][j];
        }
    }
}

// split-K reduce + bias + tanh (+ optional fp16 split emission)
__global__ void ep_tanh_s(const float* __restrict__ part, const int P,
                          const float* __restrict__ bias, float* __restrict__ dst,
                          _Float16* __restrict__ dh, _Float16* __restrict__ dl,
                          const int total, const int N)
{
    for (int i = blockIdx.x * blockDim.x + threadIdx.x; i < total;
         i += gridDim.x * blockDim.x) {
        const int n = i % N;
        float s = bias[n];
        for (int p = 0; p < P; ++p) s += part[(size_t)p * total + i];
        const float v = tanhf(s);
        dst[i] = v;
        if (dh) split16(v, dh[i], dl[i]);
    }
}

// split-K reduce + biases + LSTM gate pointwise + fp16 split emission
__global__ void ep_gate_s(const float* __restrict__ part, const int P,
                          const float* __restrict__ bih, const float* __restrict__ bhh,
                          float* __restrict__ h, float* __restrict__ c,
                          _Float16* __restrict__ hh, _Float16* __restrict__ hl,
                          _Float16* __restrict__ ch, _Float16* __restrict__ cl)
{
    const int i = blockIdx.x * blockDim.x + threadIdx.x;
    if (i >= BB * HH) return;
    const int b = i >> 10, k = i & (HH - 1);
    const size_t base = (size_t)b * 4 * HH;
    float gi = bih[k] + bhh[k];
    float gf = bih[HH + k] + bhh[HH + k];
    float gg = bih[2 * HH + k] + bhh[2 * HH + k];
    float go = bih[3 * HH + k] + bhh[3 * HH + k];
    for (int p = 0; p < P; ++p) {
        const float* gp = part + (size_t)p * BB * 4 * HH + base;
        gi += gp[k]; gf += gp[HH + k]; gg += gp[2 * HH + k]; go += gp[3 * HH + k];
    }
    const float si = 1.f / (1.f + expf(-gi));
    const float sf = 1.f / (1.f + expf(-gf));
    const float so = 1.f / (1.f + expf(-go));
    const float cn = sf * c[i] + si * tanhf(gg);
    const float hn = so * tanhf(cn);
    c[i] = cn;
    h[i] = hn;
    split16(hn, hh[i], hl[i]);
    if (ch) split16(cn, ch[i], cl[i]);
}

// ===========================================================================
extern "C" void kernel_launch(void* const* d_in, const int* in_sizes, int n_in,
                              void* d_out, int out_size, void* d_ws, size_t ws_size,
                              hipStream_t stream)
{
    const int*   y         = (const int*)  d_in[0];
    const float* enc       = (const float*)d_in[1];
    const float* esum      = (const float*)d_in[2];
    const float* emb_table = (const float*)d_in[3];
    const float* W_init    = (const float*)d_in[4];
    const float* b_init    = (const float*)d_in[5];
    const float* W_ci      = (const float*)d_in[6];
    const float* b_ci      = (const float*)d_in[7];
    const float* Wih0      = (const float*)d_in[8];
    const float* Whh0      = (const float*)d_in[9];
    const float* bih0      = (const float*)d_in[10];
    const float* bhh0      = (const float*)d_in[11];
    const float* Wih1      = (const float*)d_in[12];
    const float* Whh1      = (const float*)d_in[13];
    const float* bih1      = (const float*)d_in[14];
    const float* bhh1      = (const float*)d_in[15];
    const float* Wq        = (const float*)d_in[16];
    const float* bq        = (const float*)d_in[17];
    const float* Wco       = (const float*)d_in[18];
    const float* bco       = (const float*)d_in[19];
    const float* Wout      = (const float*)d_in[20];
    const float* bout      = (const float*)d_in[21];

    float* out    = (float*)d_out;
    float* tokens = out;
    float* logits = out + (size_t)BB * TT;

    // ---- workspace carve ----
    char* wsb = (char*)d_ws;
    size_t off = 0;
    auto alloc = [&](size_t bytes) -> char* {
        char* p = wsb + off;
        off = (off + bytes + 255) & ~(size_t)255;
        return p;
    };
    float* h0    = (float*)alloc((size_t)BB * HH * 4);
    float* h1    = (float*)alloc((size_t)BB * HH * 4);
    float* c0    = (float*)alloc((size_t)BB * HH * 4);
    float* c1    = (float*)alloc((size_t)BB * HH * 4);
    float* cross = (float*)alloc((size_t)BB * ENCE * 4);
    float* xbuf  = (float*)alloc((size_t)BB * EE * 4);
    float* embb  = (float*)alloc((size_t)BB * EE * 4);
    float* gbuf  = (float*)alloc((size_t)BB * 4 * HH * 4);
    float* qbuf  = (float*)alloc((size_t)BB * ENCE * 4);

    float* part = (float*)alloc((size_t)4 * BB * 4 * HH * 4);   // 16 MiB

    // fp16 weight splits, row-major [N][ld]
    _Float16 *ci_h, *ci_l, *g0_h, *g0_l, *g1_h, *g1_l, *wq_h, *wq_l, *wc_h, *wc_l;
    ci_h = (_Float16*)alloc((size_t)EE * 1536 * 2);
    ci_l = (_Float16*)alloc((size_t)EE * 1536 * 2);
    g0_h = (_Float16*)alloc((size_t)4 * HH * 1536 * 2);
    g0_l = (_Float16*)alloc((size_t)4 * HH * 1536 * 2);
    g1_h = (_Float16*)alloc((size_t)4 * HH * 2048 * 2);
    g1_l = (_Float16*)alloc((size_t)4 * HH * 2048 * 2);
    wq_h = (_Float16*)alloc((size_t)ENCE * 2048 * 2);
    wq_l = (_Float16*)alloc((size_t)ENCE * 2048 * 2);
    wc_h = (_Float16*)alloc((size_t)HH * 2048 * 2);
    wc_l = (_Float16*)alloc((size_t)HH * 2048 * 2);

    // fp16 activation splits
    _Float16* embh = (_Float16*)alloc((size_t)BB * EE * 2);
    _Float16* embl = (_Float16*)alloc((size_t)BB * EE * 2);
    _Float16* xbh  = (_Float16*)alloc((size_t)BB * EE * 2);
    _Float16* xbl  = (_Float16*)alloc((size_t)BB * EE * 2);
    _Float16* h0h  = (_Float16*)alloc((size_t)BB * HH * 2);
    _Float16* h0l  = (_Float16*)alloc((size_t)BB * HH * 2);
    _Float16* h1h  = (_Float16*)alloc((size_t)BB * HH * 2);
    _Float16* h1l  = (_Float16*)alloc((size_t)BB * HH * 2);
    _Float16* c1h  = (_Float16*)alloc((size_t)BB * HH * 2);
    _Float16* c1l  = (_Float16*)alloc((size_t)BB * HH * 2);
    _Float16* crh  = (_Float16*)alloc((size_t)BB * ENCE * 2);
    _Float16* crl  = (_Float16*)alloc((size_t)BB * ENCE * 2);
    const size_t need_mfma = off;

    const int mfma_ok = (ws_size >= need_mfma);

    const dim3 thr(256);

    // ---- decoder_init (fp32, once) ----
    gemm2<<<dim3(4 * HH / 64, BB / 64), thr, 0, stream>>>(
        esum, W_init, SUME, SUME, SUME,
        nullptr, nullptr, SUME, 0, 0,
        b_init, nullptr, gbuf, 4 * HH, 1);
    scatter_init_s<<<dim3(BB * 4 * HH / 256), thr, 0, stream>>>(
        gbuf, h0, h1, c0, c1,
        mfma_ok ? h0h : nullptr, h0l, h1h, h1l, c1h, c1l);
    zero_kernel<<<dim3(BB * ENCE / 256), thr, 0, stream>>>(cross, BB * ENCE);

    if (!mfma_ok) {
        for (int t = 0; t < TT; ++t) {
            gather_emb<<<dim3(BB * EE / 256), thr, 0, stream>>>(y, emb_table, embb, t);
            gemm2<<<dim3(EE / 64, BB / 64), thr, 0, stream>>>(
                embb, W_ci, EE, EE, EE + ENCE,
                cross, W_ci + EE, EE + ENCE, ENCE, EE + ENCE,
                b_ci, nullptr, xbuf, EE, 1);
            gemm2<<<dim3(4 * HH / 64, BB / 64), thr, 0, stream>>>(
                xbuf, Wih0, EE, EE, EE,
                h0, Whh0, EE + HH, HH, HH,
                bih0, bhh0, gbuf, 4 * HH, 0);
            lstm_gate<<<dim3(BB * HH / 256), thr, 0, stream>>>(gbuf, h0, c0);
            gemm2<<<dim3(4 * HH / 64, BB / 64), thr, 0, stream>>>(
                h0, Wih1, HH, HH, HH,
                h1, Whh1, 2 * HH, HH, HH,
                bih1, bhh1, gbuf, 4 * HH, 0);
            lstm_gate<<<dim3(BB * HH / 256), thr, 0, stream>>>(gbuf, h1, c1);
            gemm2<<<dim3(ENCE / 64, BB / 64), thr, 0, stream>>>(
                h1, Wq, HH, HH, 2 * HH,
                c1, Wq + HH, 2 * HH, HH, 2 * HH,
                bq, nullptr, qbuf, ENCE, 1);
            attn_kernel<<<dim3(BB), thr, 0, stream>>>(qbuf, enc, cross);
            gemm2<<<dim3(HH / 64, BB / 64), thr, 0, stream>>>(
                h1, Wco, HH, HH, ENCE + HH,
                cross, Wco + HH, ENCE + HH, ENCE, ENCE + HH,
                bco, nullptr, qbuf, HH, 1);
            out_kernel<<<dim3(BB), thr, 0, stream>>>(qbuf, Wout, bout, tokens, logits, t);
        }
        return;
    }

    // ---- one-time weight fp16-splits (every call; deterministic) ----
    const dim3 cg(4096);
    conv_w2<<<cg, thr, 0, stream>>>(W_ci, EE, EE + ENCE, ci_h, ci_l, 1536, 0);
    conv_w2<<<cg, thr, 0, stream>>>(Wih0, 4 * HH, EE, g0_h, g0_l, 1536, 0);
    conv_w2<<<cg, thr, 0, stream>>>(Whh0, 4 * HH, HH, g0_h, g0_l, 1536, EE);
    conv_w2<<<cg, thr, 0, stream>>>(Wih1, 4 * HH, HH, g1_h, g1_l, 2048, 0);
    conv_w2<<<cg, thr, 0, stream>>>(Whh1, 4 * HH, HH, g1_h, g1_l, 2048, HH);
    conv_w2<<<cg, thr, 0, stream>>>(Wq, ENCE, 2 * HH, wq_h, wq_l, 2048, 0);
    conv_w2<<<cg, thr, 0, stream>>>(Wco, HH, ENCE + HH, wc_h, wc_l, 2048, 0);
    // zero cross splits (cross = 0 at t=0); fp16 zero == bits zero
    zero_kernel<<<dim3(BB * ENCE / 512), thr, 0, stream>>>((float*)crh, BB * ENCE / 2);
    zero_kernel<<<dim3(BB * ENCE / 512), thr, 0, stream>>>((float*)crl, BB * ENCE / 2);

    auto gemmS = [&](const _Float16* a0h, const _Float16* a0l, int lda0,
                     const _Float16* a1h, const _Float16* a1l, int lda1, int K0,
                     const _Float16* wh, const _Float16* wl,
                     int Kt, int N, int P) {
        gemm_f16<<<dim3(N / 128, BB / 64, P), thr, 0, stream>>>(
            a0h, a0l, lda0, a1h, a1l, lda1, K0, wh, wl, Kt, part, N, Kt / P);
    };

    for (int t = 0; t < TT; ++t) {
        // emb splits
        gather_split<<<dim3(BB * EE / 256), thr, 0, stream>>>(y, emb_table, embh, embl, t);

        // x = tanh([emb | cross] @ Wci^T + b_ci)
        gemmS(embh, embl, EE, crh, crl, ENCE, EE, ci_h, ci_l, 1536, EE, 16);
        ep_tanh_s<<<dim3(512), thr, 0, stream>>>(part, 16, b_ci, xbuf, xbh, xbl,
                                                 BB * EE, EE);

        // layer0 gates
        gemmS(xbh, xbl, EE, h0h, h0l, HH, EE, g0_h, g0_l, 1536, 4 * HH, 4);
        ep_gate_s<<<dim3(BB * HH / 256), thr, 0, stream>>>(
            part, 4, bih0, bhh0, h0, c0, h0h, h0l, nullptr, nullptr);

        // layer1 gates
        gemmS(h0h, h0l, HH, h1h, h1l, HH, HH, g1_h, g1_l, 2048, 4 * HH, 4);
        ep_gate_s<<<dim3(BB * HH / 256), thr, 0, stream>>>(
            part, 4, bih1, bhh1, h1, c1, h1h, h1l, c1h, c1l);

        // q = tanh([h1 | c1] @ Wq^T + bq)
        gemmS(h1h, h1l, HH, c1h, c1l, HH, HH, wq_h, wq_l, 2048, ENCE, 8);
        ep_tanh_s<<<dim3(1024), thr, 0, stream>>>(part, 8, bq, qbuf, nullptr, nullptr,
                                                  BB * ENCE, ENCE);

        // attention -> cross (+ splits)
        attn_flash<<<dim3(BB), thr, 0, stream>>>(qbuf, enc, cross, crh, crl);

        // lin = tanh([h1 | cross] @ Wco^T + bco)  (qbuf reused as lin)
        gemmS(h1h, h1l, HH, crh, crl, ENCE, HH, wc_h, wc_l, 2048, HH, 8);
        ep_tanh_s<<<dim3(1024), thr, 0, stream>>>(part, 8, bco, qbuf, nullptr, nullptr,
                                                  BB * HH, HH);

        // logits + argmax
        out_kernel<<<dim3(BB), thr, 0, stream>>>(qbuf, Wout, bout, tokens, logits, t);
    }
}

// Round 7
// 11422.942 us; speedup vs baseline: 4.1018x; 1.5159x over previous
//
#include <hip/hip_runtime.h>
#include <math.h>

// Problem constants (match reference)
#define BB   256   // batch
#define TT   64    // timesteps
#define SS   256   // encoder seq len
#define VV   512   // vocab
#define EE   512   // embed dim
#define HH   1024  // hidden
#define ENCE 1024  // encoder dim
#define SUME 2048  // summary dim

typedef __attribute__((ext_vector_type(8))) _Float16 h8v;  // 8 fp16 (4 VGPR)
typedef __attribute__((ext_vector_type(4))) float f4v;

// fp32 -> fp16 (hi, lo*2^12) split. x ~= h + l * 2^-12, |err| <= 2^-24 |x|.
__device__ __forceinline__ void split16(float x, _Float16& h, _Float16& l) {
    h = (_Float16)x;
    l = (_Float16)((x - (float)h) * 4096.0f);
}

// ===========================================================================
// LEGACY fp32 path (known-good): decoder_init always; full fallback if ws
// too small.
// ===========================================================================
__global__ __launch_bounds__(256) void gemm2(
    const float* __restrict__ A0, const float* __restrict__ W0, const int K0,
    const int lda0, const int ldw0,
    const float* __restrict__ A1, const float* __restrict__ W1, const int Ktot,
    const int lda1, const int ldw1,
    const float* __restrict__ b0, const float* __restrict__ b1,
    float* __restrict__ C, const int ldc, const int act)
{
    __shared__ float As[16][68];
    __shared__ float Ws[16][68];

    const int tid = threadIdx.x;
    const int n0  = blockIdx.x * 64;
    const int m0  = blockIdx.y * 64;
    const int lr  = tid >> 2;
    const int lc  = (tid & 3) << 2;
    const int tx  = tid & 15;
    const int ty  = tid >> 4;

    float acc[4][4] = {{0.f}};

    for (int k0 = 0; k0 < Ktot; k0 += 16) {
        const float* A; const float* W; int lda, ldw, kk;
        if (k0 < K0) { A = A0; W = W0; lda = lda0; ldw = ldw0; kk = k0; }
        else         { A = A1; W = W1; lda = lda1; ldw = ldw1; kk = k0 - K0; }

        const float4 av = *(const float4*)(A + (size_t)(m0 + lr) * lda + kk + lc);
        const float4 wv = *(const float4*)(W + (size_t)(n0 + lr) * ldw + kk + lc);

        __syncthreads();
        As[lc + 0][lr] = av.x; As[lc + 1][lr] = av.y;
        As[lc + 2][lr] = av.z; As[lc + 3][lr] = av.w;
        Ws[lc + 0][lr] = wv.x; Ws[lc + 1][lr] = wv.y;
        Ws[lc + 2][lr] = wv.z; Ws[lc + 3][lr] = wv.w;
        __syncthreads();

        #pragma unroll
        for (int p = 0; p < 16; ++p) {
            const float4 a4 = *(const float4*)&As[p][ty * 4];
            const float4 w4 = *(const float4*)&Ws[p][tx * 4];
            acc[0][0] += a4.x * w4.x; acc[0][1] += a4.x * w4.y;
            acc[0][2] += a4.x * w4.z; acc[0][3] += a4.x * w4.w;
            acc[1][0] += a4.y * w4.x; acc[1][1] += a4.y * w4.y;
            acc[1][2] += a4.y * w4.z; acc[1][3] += a4.y * w4.w;
            acc[2][0] += a4.z * w4.x; acc[2][1] += a4.z * w4.y;
            acc[2][2] += a4.z * w4.z; acc[2][3] += a4.z * w4.w;
            acc[3][0] += a4.w * w4.x; acc[3][1] += a4.w * w4.y;
            acc[3][2] += a4.w * w4.z; acc[3][3] += a4.w * w4.w;
        }
    }

    float bias[4];
    #pragma unroll
    for (int j = 0; j < 4; ++j) {
        const int n = n0 + tx * 4 + j;
        bias[j] = b0[n] + (b1 ? b1[n] : 0.f);
    }
    #pragma unroll
    for (int i = 0; i < 4; ++i) {
        const int m = m0 + ty * 4 + i;
        #pragma unroll
        for (int j = 0; j < 4; ++j) {
            float v = acc[i][j] + bias[j];
            if (act) v = tanhf(v);
            C[(size_t)m * ldc + n0 + tx * 4 + j] = v;
        }
    }
}

__global__ void lstm_gate(const float* __restrict__ g,
                          float* __restrict__ h, float* __restrict__ c)
{
    const int i = blockIdx.x * blockDim.x + threadIdx.x;
    if (i >= BB * HH) return;
    const int b = i / HH, k = i % HH;
    const float* gb = g + (size_t)b * 4 * HH;
    const float gi = gb[k];
    const float gf = gb[HH + k];
    const float gg = gb[2 * HH + k];
    const float go = gb[3 * HH + k];
    const float si = 1.f / (1.f + expf(-gi));
    const float sf = 1.f / (1.f + expf(-gf));
    const float so = 1.f / (1.f + expf(-go));
    const float cn = sf * c[i] + si * tanhf(gg);
    c[i] = cn;
    h[i] = so * tanhf(cn);
}

// Legacy two-pass fp32 attention (fallback path only).
__global__ __launch_bounds__(256) void attn_kernel(
    const float* __restrict__ q, const float* __restrict__ enc,
    float* __restrict__ cross)
{
    const int b = blockIdx.x, tid = threadIdx.x;
    __shared__ float qs[ENCE];
    __shared__ float sc[SS];
    __shared__ float red[256];

    const float* qb = q + (size_t)b * ENCE;
    const float* eb = enc + (size_t)b * SS * ENCE;

    for (int e = tid; e < ENCE; e += 256) qs[e] = qb[e];
    __syncthreads();

    {
        const float* row = eb + (size_t)tid * ENCE;
        float a = 0.f;
        for (int e = 0; e < ENCE; e += 4) {
            const float4 ev = *(const float4*)&row[e];
            a += ev.x * qs[e] + ev.y * qs[e + 1] + ev.z * qs[e + 2] + ev.w * qs[e + 3];
        }
        sc[tid] = a;
    }
    __syncthreads();

    red[tid] = sc[tid];
    __syncthreads();
    for (int off = 128; off > 0; off >>= 1) {
        if (tid < off) red[tid] = fmaxf(red[tid], red[tid + off]);
        __syncthreads();
    }
    const float mx = red[0];
    __syncthreads();
    const float ex = expf(sc[tid] - mx);
    red[tid] = ex;
    __syncthreads();
    for (int off = 128; off > 0; off >>= 1) {
        if (tid < off) red[tid] += red[tid + off];
        __syncthreads();
    }
    const float inv = 1.f / red[0];
    __syncthreads();
    sc[tid] = ex * inv;
    __syncthreads();

    float4 acc = {0.f, 0.f, 0.f, 0.f};
    const int e0 = tid * 4;
    for (int s = 0; s < SS; ++s) {
        const float w = sc[s];
        const float4 ev = *(const float4*)&eb[(size_t)s * ENCE + e0];
        acc.x += w * ev.x; acc.y += w * ev.y; acc.z += w * ev.z; acc.w += w * ev.w;
    }
    *(float4*)&cross[(size_t)b * ENCE + e0] = acc;
}

// ---------------------------------------------------------------------------
// Split-flash attention: grid (4, BB). Block (sp,b) handles s-rows
// [sp*64, sp*64+64) in 8-row LDS chunks (36 KB -> 4 blocks/CU), emits
// unnormalized partial (m, l, o).
// ---------------------------------------------------------------------------
__global__ __launch_bounds__(256) void attn_part_k(
    const float* __restrict__ q, const float* __restrict__ enc,
    float* __restrict__ po, float* __restrict__ pm, float* __restrict__ pl)
{
    const int sp = blockIdx.x, b = blockIdx.y, tid = threadIdx.x;
    __shared__ float qs[ENCE];
    __shared__ float es[8 * ENCE];   // 32 KB
    __shared__ float sc[8];

    const float* qb = q + (size_t)b * ENCE;
    const float* eb = enc + (size_t)b * SS * ENCE + (size_t)sp * 64 * ENCE;

    *(float4*)&qs[tid * 4] = *(const float4*)&qb[tid * 4];
    __syncthreads();

    const int sl  = tid >> 5;    // 0..7 : row for score phase
    const int seg = tid & 31;    // 0..31: column group
    const int e0  = tid * 4;

    float m = -INFINITY, l = 0.f;
    float4 o = {0.f, 0.f, 0.f, 0.f};

    for (int ch = 0; ch < 8; ++ch) {
        {   // stage 8 rows, fully coalesced
            const float* src = eb + (size_t)ch * 8 * ENCE;
            #pragma unroll
            for (int i = 0; i < 8; ++i) {
                const int idx = tid * 4 + i * 1024;
                *(float4*)&es[idx] = *(const float4*)&src[idx];
            }
        }
        __syncthreads();

        {   // scores: 32 threads per row
            float a = 0.f;
            const float* row = &es[sl * ENCE];
            #pragma unroll
            for (int j = 0; j < 8; ++j) {
                const int e = seg * 4 + j * 128;
                const float4 ev = *(const float4*)&row[e];
                const float4 qv = *(const float4*)&qs[e];
                a += ev.x * qv.x + ev.y * qv.y + ev.z * qv.z + ev.w * qv.w;
            }
            a += __shfl_xor(a, 1, 32);
            a += __shfl_xor(a, 2, 32);
            a += __shfl_xor(a, 4, 32);
            a += __shfl_xor(a, 8, 32);
            a += __shfl_xor(a, 16, 32);
            if (seg == 0) sc[sl] = a;
        }
        __syncthreads();

        {   // online softmax update (block-uniform m, l)
            float cm = sc[0];
            #pragma unroll
            for (int i = 1; i < 8; ++i) cm = fmaxf(cm, sc[i]);
            const float mn = fmaxf(m, cm);
            const float scale = expf(m - mn);
            o.x *= scale; o.y *= scale; o.z *= scale; o.w *= scale;
            l *= scale;
            float p[8];
            #pragma unroll
            for (int i = 0; i < 8; ++i) { p[i] = expf(sc[i] - mn); l += p[i]; }
            #pragma unroll
            for (int i = 0; i < 8; ++i) {
                const float4 ev = *(const float4*)&es[i * ENCE + e0];
                o.x += p[i] * ev.x; o.y += p[i] * ev.y;
                o.z += p[i] * ev.z; o.w += p[i] * ev.w;
            }
            m = mn;
        }
        __syncthreads();
    }

    *(float4*)&po[((size_t)sp * BB + b) * ENCE + e0] = o;
    if (tid == 0) { pm[sp * BB + b] = m; pl[sp * BB + b] = l; }
}

// Combine 4 flash partials -> cross (fp16 splits only; MFMA path).
__global__ __launch_bounds__(256) void attn_comb_k(
    const float* __restrict__ po, const float* __restrict__ pm,
    const float* __restrict__ pl,
    _Float16* __restrict__ crh, _Float16* __restrict__ crl)
{
    const int b = blockIdx.x, tid = threadIdx.x;
    float m0 = pm[b], m1 = pm[BB + b], m2 = pm[2 * BB + b], m3 = pm[3 * BB + b];
    const float ms = fmaxf(fmaxf(m0, m1), fmaxf(m2, m3));
    const float w0 = expf(m0 - ms), w1 = expf(m1 - ms);
    const float w2 = expf(m2 - ms), w3 = expf(m3 - ms);
    const float L = pl[b] * w0 + pl[BB + b] * w1 + pl[2 * BB + b] * w2 +
                    pl[3 * BB + b] * w3;
    const float inv = 1.f / L;

    const int e0 = tid * 4;
    const float4 o0 = *(const float4*)&po[((size_t)0 * BB + b) * ENCE + e0];
    const float4 o1 = *(const float4*)&po[((size_t)1 * BB + b) * ENCE + e0];
    const float4 o2 = *(const float4*)&po[((size_t)2 * BB + b) * ENCE + e0];
    const float4 o3 = *(const float4*)&po[((size_t)3 * BB + b) * ENCE + e0];
    float4 r;
    r.x = (o0.x * w0 + o1.x * w1 + o2.x * w2 + o3.x * w3) * inv;
    r.y = (o0.y * w0 + o1.y * w1 + o2.y * w2 + o3.y * w3) * inv;
    r.z = (o0.z * w0 + o1.z * w1 + o2.z * w2 + o3.z * w3) * inv;
    r.w = (o0.w * w0 + o1.w * w1 + o2.w * w2 + o3.w * w3) * inv;

    _Float16 h4[4], l4[4];
    split16(r.x, h4[0], l4[0]); split16(r.y, h4[1], l4[1]);
    split16(r.z, h4[2], l4[2]); split16(r.w, h4[3], l4[3]);
    *(uint2*)&crh[(size_t)b * ENCE + e0] = *(uint2*)h4;
    *(uint2*)&crl[(size_t)b * ENCE + e0] = *(uint2*)l4;
}

// Legacy fallback out projection (fallback path only).
__global__ __launch_bounds__(256) void out_kernel(
    const float* __restrict__ lin, const float* __restrict__ Wout,
    const float* __restrict__ bout, float* __restrict__ tokens,
    float* __restrict__ logits, const int t)
{
    const int b = blockIdx.x, tid = threadIdx.x;
    __shared__ float ls[HH];
    __shared__ float vmax[256];
    __shared__ int   vidx[256];

    const float* lb = lin + (size_t)b * HH;
    for (int e = tid; e < HH; e += 256) ls[e] = lb[e];
    __syncthreads();

    float best = -INFINITY; int bi = 0;
    for (int n = tid; n < VV; n += 256) {
        const float* wr = Wout + (size_t)n * HH;
        float a = bout[n];
        for (int e = 0; e < HH; e += 4) {
            const float4 wv = *(const float4*)&wr[e];
            a += wv.x * ls[e] + wv.y * ls[e + 1] + wv.z * ls[e + 2] + wv.w * ls[e + 3];
        }
        logits[((size_t)b * TT + t) * VV + n] = a;
        if (a > best) { best = a; bi = n; }
    }
    vmax[tid] = best; vidx[tid] = bi;
    __syncthreads();
    for (int off = 128; off > 0; off >>= 1) {
        if (tid < off) {
            const float vo = vmax[tid + off]; const int io = vidx[tid + off];
            if (vo > vmax[tid] || (vo == vmax[tid] && io < vidx[tid])) {
                vmax[tid] = vo; vidx[tid] = io;
            }
        }
        __syncthreads();
    }
    if (tid == 0) tokens[(size_t)b * TT + t] = (float)vidx[0];
}

__global__ void gather_emb(const int* __restrict__ y,
                           const float* __restrict__ table,
                           float* __restrict__ emb, const int t)
{
    const int i = blockIdx.x * blockDim.x + threadIdx.x;
    if (i >= BB * EE) return;
    const int b = i / EE, e = i % EE;
    emb[i] = table[(size_t)y[(size_t)b * TT + t] * EE + e];
}

// init scatter + optional fp16 splits for h0, h1, c1
__global__ void scatter_init_s(const float* __restrict__ ini,
                               float* __restrict__ h0, float* __restrict__ h1,
                               float* __restrict__ c0, float* __restrict__ c1,
                               _Float16* __restrict__ h0h, _Float16* __restrict__ h0l,
                               _Float16* __restrict__ h1h, _Float16* __restrict__ h1l,
                               _Float16* __restrict__ c1h, _Float16* __restrict__ c1l)
{
    const int i = blockIdx.x * blockDim.x + threadIdx.x;
    if (i >= BB * 4 * HH) return;
    const int b = i / (4 * HH), j = i % (4 * HH);
    const int i1 = j / (2 * HH);
    const int rem = j % (2 * HH);
    const int i2 = rem / HH;
    const int k = rem % HH;
    const float v = ini[i];
    const size_t o = (size_t)b * HH + k;
    float* dst = (i1 == 0) ? (i2 == 0 ? h0 : h1) : (i2 == 0 ? c0 : c1);
    dst[o] = v;
    if (h0h) {
        if (i1 == 0) {
            _Float16 h, l; split16(v, h, l);
            if (i2 == 0) { h0h[o] = h; h0l[o] = l; }
            else         { h1h[o] = h; h1l[o] = l; }
        } else if (i2 == 1) {
            _Float16 h, l; split16(v, h, l);
            c1h[o] = h; c1l[o] = l;
        }
    }
}

__global__ void zero_kernel(float* __restrict__ p, const int n)
{
    const int i = blockIdx.x * blockDim.x + threadIdx.x;
    if (i < n) p[i] = 0.f;
}

// ===========================================================================
// fp16 2-split MFMA path: 3 passes, 2 accumulators, fp32-grade (~2^-24).
// ===========================================================================

// fp32 weights -> fp16 (hi, lo*2^12), packed into column slice of [N][dld].
__global__ void conv_w2(const float* __restrict__ src, const int N, const int K,
                        _Float16* __restrict__ dh, _Float16* __restrict__ dl,
                        const int dld, const int coff)
{
    const int total = N * K;
    for (int i = blockIdx.x * blockDim.x + threadIdx.x; i < total;
         i += gridDim.x * blockDim.x) {
        const int n = i / K, k = i - n * K;
        const size_t o = (size_t)n * dld + coff + k;
        split16(src[i], dh[o], dl[o]);
    }
}

// Software-pipelined fp16-split MFMA GEMM, split-K partials.
// If rawA0 != null: A0-side reads fp32 rows of rawA0 at row yidx[m*TT+t]
// (fused embedding gather), split in-registers.
__global__ __launch_bounds__(256) void gemm_f16(
    const _Float16* __restrict__ A0h, const _Float16* __restrict__ A0l, const int lda0,
    const _Float16* __restrict__ A1h, const _Float16* __restrict__ A1l, const int lda1,
    const int K0,
    const float* __restrict__ rawA0, const int* __restrict__ yidx, const int t,
    const _Float16* __restrict__ Wh, const _Float16* __restrict__ Wl,
    const int Kt, float* __restrict__ Cpart, const int N, const int chunk)
{
    __shared__ _Float16 Ash[64][40], Asl[64][40];
    __shared__ _Float16 Wsh[128][40], Wsl[128][40];

    const int tid = threadIdx.x;
    const int n0 = blockIdx.x * 128;
    const int m0 = blockIdx.y * 64;
    const int p  = blockIdx.z;
    const int kbeg = p * chunk, kend = kbeg + chunk;

    const int lane = tid & 63, wave = tid >> 6;
    const int wm = wave >> 1, wn = wave & 1;
    const int l15 = lane & 15, lg = lane >> 4;

    const int ar = tid >> 2, ag = tid & 3;     // staging: row 0..63, k-grp 0..3

    const float* Araw = rawA0
        ? rawA0 + (size_t)yidx[(size_t)(m0 + ar) * TT + t] * lda0 : nullptr;

    f4v accm[2][4], accc[2][4];
    #pragma unroll
    for (int i = 0; i < 2; ++i)
        #pragma unroll
        for (int j = 0; j < 4; ++j) {
            accm[i][j] = (f4v){0.f, 0.f, 0.f, 0.f};
            accc[i][j] = (f4v){0.f, 0.f, 0.f, 0.f};
        }

    uint4 avh, avl, wh0, wl0, wh1, wl1;

    auto load_tile = [&](int kk_) {
        const int col = kk_ + ag * 8;
        if (col < K0) {
            if (Araw) {
                const float4 f0 = *(const float4*)(Araw + col);
                const float4 f1 = *(const float4*)(Araw + col + 4);
                const float xs[8] = {f0.x, f0.y, f0.z, f0.w, f1.x, f1.y, f1.z, f1.w};
                h8v vh, vl;
                #pragma unroll
                for (int j = 0; j < 8; ++j) {
                    _Float16 th, tl;
                    split16(xs[j], th, tl);
                    vh[j] = th;
                    vl[j] = tl;
                }
                avh = *(uint4*)&vh; avl = *(uint4*)&vl;
            } else {
                const size_t o = (size_t)(m0 + ar) * lda0 + col;
                avh = *(const uint4*)(A0h + o);
                avl = *(const uint4*)(A0l + o);
            }
        } else {
            const size_t o = (size_t)(m0 + ar) * lda1 + (col - K0);
            avh = *(const uint4*)(A1h + o);
            avl = *(const uint4*)(A1l + o);
        }
        const size_t o0 = (size_t)(n0 + ar) * Kt + kk_ + ag * 8;
        const size_t o1 = o0 + (size_t)64 * Kt;
        wh0 = *(const uint4*)(Wh + o0);
        wl0 = *(const uint4*)(Wl + o0);
        wh1 = *(const uint4*)(Wh + o1);
        wl1 = *(const uint4*)(Wl + o1);
    };

    load_tile(kbeg);

    for (int kk = kbeg; kk < kend; kk += 32) {
        __syncthreads();

        *(uint4*)&Ash[ar][ag * 8] = avh;
        *(uint4*)&Asl[ar][ag * 8] = avl;
        *(uint4*)&Wsh[ar][ag * 8] = wh0;
        *(uint4*)&Wsl[ar][ag * 8] = wl0;
        *(uint4*)&Wsh[64 + ar][ag * 8] = wh1;
        *(uint4*)&Wsl[64 + ar][ag * 8] = wl1;

        __syncthreads();

        if (kk + 32 < kend) load_tile(kk + 32);   // in flight under compute

        h8v afh[2], afl[2];
        #pragma unroll
        for (int fr = 0; fr < 2; ++fr) {
            const int r = wm * 32 + fr * 16 + l15;
            afh[fr] = *(const h8v*)&Ash[r][lg * 8];
            afl[fr] = *(const h8v*)&Asl[r][lg * 8];
        }
        #pragma unroll
        for (int fn = 0; fn < 4; ++fn) {
            const int r = wn * 64 + fn * 16 + l15;
            const h8v wfh = *(const h8v*)&Wsh[r][lg * 8];
            const h8v wfl = *(const h8v*)&Wsl[r][lg * 8];
            #pragma unroll
            for (int fr = 0; fr < 2; ++fr) {
                accm[fr][fn] = __builtin_amdgcn_mfma_f32_16x16x32_f16(
                    afh[fr], wfh, accm[fr][fn], 0, 0, 0);
                accc[fr][fn] = __builtin_amdgcn_mfma_f32_16x16x32_f16(
                    afh[fr], wfl, accc[fr][fn], 0, 0, 0);
                accc[fr][fn] = __builtin_amdgcn_mfma_f32_16x16x32_f16(
                    afl[fr], wfh, accc[fr][fn], 0, 0, 0);
            }
        }
    }

    const float s12 = 0.000244140625f;  // 2^-12
    float* slab = Cpart + (size_t)p * BB * N;
    #pragma unroll
    for (int fr = 0; fr < 2; ++fr) {
        const int row0 = m0 + wm * 32 + fr * 16 + lg * 4;
        #pragma unroll
        for (int fn = 0; fn < 4; ++fn) {
            const int col = n0 + wn * 64 + fn * 16 + l15;
            #pragma unroll
            for (int j = 0; j < 4; ++j)
                slab[(size_t)(row0 + j) * N + col] =
                    accm[fr][fn][j] + s12 * accc[fr][fn][j];
        }
    }
}

// split-K reduce + bias + tanh; dst and split outputs each optional
__global__ void ep_tanh_s(const float* __restrict__ part, const int P,
                          const float* __restrict__ bias, float* __restrict__ dst,
                          _Float16* __restrict__ dh, _Float16* __restrict__ dl,
                          const int total, const int N)
{
    for (int i = blockIdx.x * blockDim.x + threadIdx.x; i < total;
         i += gridDim.x * blockDim.x) {
        const int n = i % N;
        float s = bias[n];
        for (int p = 0; p < P; ++p) s += part[(size_t)p * total + i];
        const float v = tanhf(s);
        if (dst) dst[i] = v;
        if (dh) split16(v, dh[i], dl[i]);
    }
}

// split-K reduce + biases + LSTM gate pointwise + fp16 split emission
__global__ void ep_gate_s(const float* __restrict__ part, const int P,
                          const float* __restrict__ bih, const float* __restrict__ bhh,
                          float* __restrict__ h, float* __restrict__ c,
                          _Float16* __restrict__ hh, _Float16* __restrict__ hl,
                          _Float16* __restrict__ ch, _Float16* __restrict__ cl)
{
    const int i = blockIdx.x * blockDim.x + threadIdx.x;
    if (i >= BB * HH) return;
    const int b = i >> 10, k = i & (HH - 1);
    const size_t base = (size_t)b * 4 * HH;
    float gi = bih[k] + bhh[k];
    float gf = bih[HH + k] + bhh[HH + k];
    float gg = bih[2 * HH + k] + bhh[2 * HH + k];
    float go = bih[3 * HH + k] + bhh[3 * HH + k];
    for (int p = 0; p < P; ++p) {
        const float* gp = part + (size_t)p * BB * 4 * HH + base;
        gi += gp[k]; gf += gp[HH + k]; gg += gp[2 * HH + k]; go += gp[3 * HH + k];
    }
    const float si = 1.f / (1.f + expf(-gi));
    const float sf = 1.f / (1.f + expf(-gf));
    const float so = 1.f / (1.f + expf(-go));
    const float cn = sf * c[i] + si * tanhf(gg);
    const float hn = so * tanhf(cn);
    c[i] = cn;
    h[i] = hn;
    split16(hn, hh[i], hl[i]);
    if (ch) split16(cn, ch[i], cl[i]);
}

// split-K reduce + bias + logits write + first-max argmax. One block per b.
__global__ __launch_bounds__(256) void ep_argmax(
    const float* __restrict__ part, const int P,
    const float* __restrict__ bias, float* __restrict__ tokens,
    float* __restrict__ logits, const int t)
{
    const int b = blockIdx.x, tid = threadIdx.x;
    __shared__ float vmax[256];
    __shared__ int   vidx[256];

    float best = -INFINITY; int bi = 0;
    #pragma unroll
    for (int j = 0; j < 2; ++j) {
        const int n = tid + j * 256;
        float s = bias[n];
        for (int p = 0; p < P; ++p)
            s += part[(size_t)p * BB * VV + (size_t)b * VV + n];
        logits[((size_t)b * TT + t) * VV + n] = s;
        if (s > best) { best = s; bi = n; }   // ascending n: first-max kept
    }
    vmax[tid] = best; vidx[tid] = bi;
    __syncthreads();
    for (int off = 128; off > 0; off >>= 1) {
        if (tid < off) {
            const float vo = vmax[tid + off]; const int io = vidx[tid + off];
            if (vo > vmax[tid] || (vo == vmax[tid] && io < vidx[tid])) {
                vmax[tid] = vo; vidx[tid] = io;
            }
        }
        __syncthreads();
    }
    if (tid == 0) tokens[(size_t)b * TT + t] = (float)vidx[0];
}

// ===========================================================================
extern "C" void kernel_launch(void* const* d_in, const int* in_sizes, int n_in,
                              void* d_out, int out_size, void* d_ws, size_t ws_size,
                              hipStream_t stream)
{
    const int*   y         = (const int*)  d_in[0];
    const float* enc       = (const float*)d_in[1];
    const float* esum      = (const float*)d_in[2];
    const float* emb_table = (const float*)d_in[3];
    const float* W_init    = (const float*)d_in[4];
    const float* b_init    = (const float*)d_in[5];
    const float* W_ci      = (const float*)d_in[6];
    const float* b_ci      = (const float*)d_in[7];
    const float* Wih0      = (const float*)d_in[8];
    const float* Whh0      = (const float*)d_in[9];
    const float* bih0      = (const float*)d_in[10];
    const float* bhh0      = (const float*)d_in[11];
    const float* Wih1      = (const float*)d_in[12];
    const float* Whh1      = (const float*)d_in[13];
    const float* bih1      = (const float*)d_in[14];
    const float* bhh1      = (const float*)d_in[15];
    const float* Wq        = (const float*)d_in[16];
    const float* bq        = (const float*)d_in[17];
    const float* Wco       = (const float*)d_in[18];
    const float* bco       = (const float*)d_in[19];
    const float* Wout      = (const float*)d_in[20];
    const float* bout      = (const float*)d_in[21];

    float* out    = (float*)d_out;
    float* tokens = out;
    float* logits = out + (size_t)BB * TT;

    // ---- workspace carve ----
    char* wsb = (char*)d_ws;
    size_t off = 0;
    auto alloc = [&](size_t bytes) -> char* {
        char* p = wsb + off;
        off = (off + bytes + 255) & ~(size_t)255;
        return p;
    };
    float* h0    = (float*)alloc((size_t)BB * HH * 4);
    float* h1    = (float*)alloc((size_t)BB * HH * 4);
    float* c0    = (float*)alloc((size_t)BB * HH * 4);
    float* c1    = (float*)alloc((size_t)BB * HH * 4);
    float* cross = (float*)alloc((size_t)BB * ENCE * 4);
    float* xbuf  = (float*)alloc((size_t)BB * EE * 4);
    float* embb  = (float*)alloc((size_t)BB * EE * 4);
    float* gbuf  = (float*)alloc((size_t)BB * 4 * HH * 4);
    float* qbuf  = (float*)alloc((size_t)BB * ENCE * 4);

    float* part = (float*)alloc((size_t)4 * BB * 4 * HH * 4);   // 16 MiB

    // fp16 weight splits, row-major [N][ld]
    _Float16 *ci_h, *ci_l, *g0_h, *g0_l, *g1_h, *g1_l, *wq_h, *wq_l,
             *wc_h, *wc_l, *wo_h, *wo_l;
    ci_h = (_Float16*)alloc((size_t)EE * 1536 * 2);
    ci_l = (_Float16*)alloc((size_t)EE * 1536 * 2);
    g0_h = (_Float16*)alloc((size_t)4 * HH * 1536 * 2);
    g0_l = (_Float16*)alloc((size_t)4 * HH * 1536 * 2);
    g1_h = (_Float16*)alloc((size_t)4 * HH * 2048 * 2);
    g1_l = (_Float16*)alloc((size_t)4 * HH * 2048 * 2);
    wq_h = (_Float16*)alloc((size_t)ENCE * 2048 * 2);
    wq_l = (_Float16*)alloc((size_t)ENCE * 2048 * 2);
    wc_h = (_Float16*)alloc((size_t)HH * 2048 * 2);
    wc_l = (_Float16*)alloc((size_t)HH * 2048 * 2);
    wo_h = (_Float16*)alloc((size_t)VV * HH * 2);
    wo_l = (_Float16*)alloc((size_t)VV * HH * 2);

    // fp16 activation splits
    _Float16* xbh  = (_Float16*)alloc((size_t)BB * EE * 2);
    _Float16* xbl  = (_Float16*)alloc((size_t)BB * EE * 2);
    _Float16* h0h  = (_Float16*)alloc((size_t)BB * HH * 2);
    _Float16* h0l  = (_Float16*)alloc((size_t)BB * HH * 2);
    _Float16* h1h  = (_Float16*)alloc((size_t)BB * HH * 2);
    _Float16* h1l  = (_Float16*)alloc((size_t)BB * HH * 2);
    _Float16* c1h  = (_Float16*)alloc((size_t)BB * HH * 2);
    _Float16* c1l  = (_Float16*)alloc((size_t)BB * HH * 2);
    _Float16* crh  = (_Float16*)alloc((size_t)BB * ENCE * 2);
    _Float16* crl  = (_Float16*)alloc((size_t)BB * ENCE * 2);
    _Float16* lnh  = (_Float16*)alloc((size_t)BB * HH * 2);
    _Float16* lnl  = (_Float16*)alloc((size_t)BB * HH * 2);

    // attention partials
    float* po = (float*)alloc((size_t)4 * BB * ENCE * 4);
    float* pm = (float*)alloc((size_t)4 * BB * 4);
    float* pl = (float*)alloc((size_t)4 * BB * 4);
    const size_t need_mfma = off;

    const int mfma_ok = (ws_size >= need_mfma);

    const dim3 thr(256);

    // ---- decoder_init (fp32, once) ----
    gemm2<<<dim3(4 * HH / 64, BB / 64), thr, 0, stream>>>(
        esum, W_init, SUME, SUME, SUME,
        nullptr, nullptr, SUME, 0, 0,
        b_init, nullptr, gbuf, 4 * HH, 1);
    scatter_init_s<<<dim3(BB * 4 * HH / 256), thr, 0, stream>>>(
        gbuf, h0, h1, c0, c1,
        mfma_ok ? h0h : nullptr, h0l, h1h, h1l, c1h, c1l);
    zero_kernel<<<dim3(BB * ENCE / 256), thr, 0, stream>>>(cross, BB * ENCE);

    if (!mfma_ok) {
        for (int t = 0; t < TT; ++t) {
            gather_emb<<<dim3(BB * EE / 256), thr, 0, stream>>>(y, emb_table, embb, t);
            gemm2<<<dim3(EE / 64, BB / 64), thr, 0, stream>>>(
                embb, W_ci, EE, EE, EE + ENCE,
                cross, W_ci + EE, EE + ENCE, ENCE, EE + ENCE,
                b_ci, nullptr, xbuf, EE, 1);
            gemm2<<<dim3(4 * HH / 64, BB / 64), thr, 0, stream>>>(
                xbuf, Wih0, EE, EE, EE,
                h0, Whh0, EE + HH, HH, HH,
                bih0, bhh0, gbuf, 4 * HH, 0);
            lstm_gate<<<dim3(BB * HH / 256), thr, 0, stream>>>(gbuf, h0, c0);
            gemm2<<<dim3(4 * HH / 64, BB / 64), thr, 0, stream>>>(
                h0, Wih1, HH, HH, HH,
                h1, Whh1, 2 * HH, HH, HH,
                bih1, bhh1, gbuf, 4 * HH, 0);
            lstm_gate<<<dim3(BB * HH / 256), thr, 0, stream>>>(gbuf, h1, c1);
            gemm2<<<dim3(ENCE / 64, BB / 64), thr, 0, stream>>>(
                h1, Wq, HH, HH, 2 * HH,
                c1, Wq + HH, 2 * HH, HH, 2 * HH,
                bq, nullptr, qbuf, ENCE, 1);
            attn_kernel<<<dim3(BB), thr, 0, stream>>>(qbuf, enc, cross);
            gemm2<<<dim3(HH / 64, BB / 64), thr, 0, stream>>>(
                h1, Wco, HH, HH, ENCE + HH,
                cross, Wco + HH, ENCE + HH, ENCE, ENCE + HH,
                bco, nullptr, qbuf, HH, 1);
            out_kernel<<<dim3(BB), thr, 0, stream>>>(qbuf, Wout, bout, tokens, logits, t);
        }
        return;
    }

    // ---- one-time weight fp16-splits ----
    const dim3 cg(4096);
    conv_w2<<<cg, thr, 0, stream>>>(W_ci, EE, EE + ENCE, ci_h, ci_l, 1536, 0);
    conv_w2<<<cg, thr, 0, stream>>>(Wih0, 4 * HH, EE, g0_h, g0_l, 1536, 0);
    conv_w2<<<cg, thr, 0, stream>>>(Whh0, 4 * HH, HH, g0_h, g0_l, 1536, EE);
    conv_w2<<<cg, thr, 0, stream>>>(Wih1, 4 * HH, HH, g1_h, g1_l, 2048, 0);
    conv_w2<<<cg, thr, 0, stream>>>(Whh1, 4 * HH, HH, g1_h, g1_l, 2048, HH);
    conv_w2<<<cg, thr, 0, stream>>>(Wq, ENCE, 2 * HH, wq_h, wq_l, 2048, 0);
    conv_w2<<<cg, thr, 0, stream>>>(Wco, HH, ENCE + HH, wc_h, wc_l, 2048, 0);
    conv_w2<<<cg, thr, 0, stream>>>(Wout, VV, HH, wo_h, wo_l, HH, 0);
    // cross = 0 at t=0 (fp16 zero == bits zero)
    zero_kernel<<<dim3(BB * ENCE / 512), thr, 0, stream>>>((float*)crh, BB * ENCE / 2);
    zero_kernel<<<dim3(BB * ENCE / 512), thr, 0, stream>>>((float*)crl, BB * ENCE / 2);

    auto gemmS = [&](const _Float16* a0h, const _Float16* a0l, int lda0,
                     const _Float16* a1h, const _Float16* a1l, int lda1, int K0,
                     const float* raw0, const int* yi, int t_,
                     const _Float16* wh, const _Float16* wl,
                     int Kt, int N, int P) {
        gemm_f16<<<dim3(N / 128, BB / 64, P), thr, 0, stream>>>(
            a0h, a0l, lda0, a1h, a1l, lda1, K0, raw0, yi, t_,
            wh, wl, Kt, part, N, Kt / P);
    };

    for (int t = 0; t < TT; ++t) {
        // x = tanh([emb_table[y[:,t]] | cross] @ Wci^T + b_ci)  (fused gather)
        gemmS(nullptr, nullptr, EE, crh, crl, ENCE, EE,
              emb_table, y, t, ci_h, ci_l, 1536, EE, 8);
        ep_tanh_s<<<dim3(512), thr, 0, stream>>>(part, 8, b_ci, nullptr, xbh, xbl,
                                                 BB * EE, EE);

        // layer0 gates
        gemmS(xbh, xbl, EE, h0h, h0l, HH, EE, nullptr, nullptr, 0,
              g0_h, g0_l, 1536, 4 * HH, 4);
        ep_gate_s<<<dim3(BB * HH / 256), thr, 0, stream>>>(
            part, 4, bih0, bhh0, h0, c0, h0h, h0l, nullptr, nullptr);

        // layer1 gates
        gemmS(h0h, h0l, HH, h1h, h1l, HH, HH, nullptr, nullptr, 0,
              g1_h, g1_l, 2048, 4 * HH, 4);
        ep_gate_s<<<dim3(BB * HH / 256), thr, 0, stream>>>(
            part, 4, bih1, bhh1, h1, c1, h1h, h1l, c1h, c1l);

        // q = tanh([h1 | c1] @ Wq^T + bq)  (fp32 q for attention)
        gemmS(h1h, h1l, HH, c1h, c1l, HH, HH, nullptr, nullptr, 0,
              wq_h, wq_l, 2048, ENCE, 8);
        ep_tanh_s<<<dim3(1024), thr, 0, stream>>>(part, 8, bq, qbuf, nullptr, nullptr,
                                                  BB * ENCE, ENCE);

        // attention: split-flash partials + combine -> cross splits
        attn_part_k<<<dim3(4, BB), thr, 0, stream>>>(qbuf, enc, po, pm, pl);
        attn_comb_k<<<dim3(BB), thr, 0, stream>>>(po, pm, pl, crh, crl);

        // lin = tanh([h1 | cross] @ Wco^T + bco) -> splits only
        gemmS(h1h, h1l, HH, crh, crl, ENCE, HH, nullptr, nullptr, 0,
              wc_h, wc_l, 2048, HH, 8);
        ep_tanh_s<<<dim3(1024), thr, 0, stream>>>(part, 8, bco, nullptr, lnh, lnl,
                                                  BB * HH, HH);

        // logits GEMM + fused argmax epilogue
        gemmS(lnh, lnl, HH, nullptr, nullptr, HH, HH, nullptr, nullptr, 0,
              wo_h, wo_l, HH, VV, 8);
        ep_argmax<<<dim3(BB), thr, 0, stream>>>(part, 8, bout, tokens, logits, t);
    }
}